// Round 8
// baseline (451.814 us; speedup 1.0000x reference)
//
#include <hip/hip_runtime.h>
#include <hip/hip_bf16.h>
#include <cstdio>
#include <cstdint>

#define TNUM 2048
#define DDIM 768
#define HDIM 3072
#define ENUM 8

#define WAITVM(N) asm volatile("s_waitcnt vmcnt(" #N ")" ::: "memory")
#define WAITLGKM() asm volatile("s_waitcnt lgkmcnt(0)" ::: "memory")
#define MEMFENCE() asm volatile("" ::: "memory")

typedef __attribute__((ext_vector_type(8))) __bf16 bf16x8;
typedef __attribute__((ext_vector_type(4))) float f32x4;

__device__ __forceinline__ unsigned short f2bf(float f) {
    __bf16 h = (__bf16)f;            // RNE
    unsigned short u;
    __builtin_memcpy(&u, &h, 2);
    return u;
}

__device__ __forceinline__ void async_cp16(const unsigned short* g, unsigned short* l) {
    __builtin_amdgcn_global_load_lds((const __attribute__((address_space(1))) void*)g,
                                     (__attribute__((address_space(3))) void*)l,
                                     16, 0, 0);
}

// ---------------- 128x128 transpose+cast tile (W2/Ws2 only) ----------------
__device__ __forceinline__ void transpose_tile(const float* __restrict__ in,
                                               unsigned short* __restrict__ out,
                                               int R, int C, int c0, int r0,
                                               unsigned int* tileT32) {
    int tid = threadIdx.x;
    int l15 = tid & 15;
    int g = tid >> 4;
    int par = (g >> 1) & 1;
    int hf = g & 1;
    int cb = hf * 64 + l15 * 4;
    const float* src = in + (size_t)(r0 + (g >> 1)) * C + c0 + cb;
    float4 v[16];
    #pragma unroll
    for (int p = 0; p < 16; p++)
        v[p] = *(const float4*)(src + (size_t)p * 8 * C);
    #pragma unroll
    for (int p = 0; p < 16; p++) {
        int unit = p * 16 + g;
        unsigned int m01 = (unsigned int)f2bf(v[p].x) | ((unsigned int)f2bf(v[p].y) << 16);
        unsigned int m23 = (unsigned int)f2bf(v[p].z) | ((unsigned int)f2bf(v[p].w) << 16);
        unsigned int o01 = __shfl_xor(m01, 32);
        unsigned int o23 = __shfl_xor(m23, 32);
        unsigned int wA = par ? ((o23 & 0xffffu) | (m23 << 16))
                              : ((m01 & 0xffffu) | (o01 << 16));
        unsigned int wB = par ? ((o23 >> 16) | (m23 & 0xffff0000u))
                              : ((m01 >> 16) | (o01 & 0xffff0000u));
        int ca = cb + par * 2;
        int rp = unit >> 2;
        int cq = ca >> 2;
        int woff = 4 * (((rp >> 2) + 3 * cq) & 15) + (((rp & 3) + cq) & 3);
        tileT32[ca * 68 + woff] = wA;
        tileT32[(ca + 1) * 68 + woff] = wB;
    }
    __syncthreads();
    uint4 Wv[8];
    #pragma unroll
    for (int p = 0; p < 8; p++) {
        int cc = p * 16 + g;
        int cqp = cc >> 2;
        Wv[p] = *(const uint4*)&tileT32[cc * 68 + 4 * ((l15 + 3 * cqp) & 15)];
    }
    #pragma unroll
    for (int p = 0; p < 8; p++) {
        int cc = p * 16 + g;
        int cqp = cc >> 2;
        unsigned int a0 = Wv[p].x, a1 = Wv[p].y, a2 = Wv[p].z, a3 = Wv[p].w;
        int rsel = cqp & 3;
        if (rsel & 1) { unsigned int t = a0; a0 = a1; a1 = a2; a2 = a3; a3 = t; }
        if (rsel & 2) { unsigned int t0 = a0, t1 = a1; a0 = a2; a1 = a3; a2 = t0; a3 = t1; }
        uint4 ov; ov.x = a0; ov.y = a1; ov.z = a2; ov.w = a3;
        *(uint4*)(out + (size_t)(c0 + cc) * R + r0 + l15 * 8) = ov;
    }
}

// ---------------- kernel 1: transw(W2,Ws2) || cast_x || router ----------------
__global__ __launch_bounds__(256, 4)
void pre_kernel(const float* __restrict__ x, const float* __restrict__ noise,
                const float* __restrict__ Wr, const float* __restrict__ br,
                const float* __restrict__ W2, const float* __restrict__ Ws2,
                unsigned short* __restrict__ W2t, unsigned short* __restrict__ Ws2t,
                unsigned short* __restrict__ xb,
                int* __restrict__ counts, int* __restrict__ list,
                int* __restrict__ inv, float* __restrict__ tokp) {
    __shared__ __align__(16) unsigned int tileT32[128 * 68];
    int b = blockIdx.x;
    if (b < 1296) {
        int m = b / 144, t = b % 144;   // 9 matrices (W2[0..7], Ws2)
        const float* in     = (m < 8) ? (W2 + (size_t)m * HDIM * DDIM) : Ws2;
        unsigned short* out = (m < 8) ? (W2t + (size_t)m * DDIM * HDIM) : Ws2t;
        transpose_tile(in, out, HDIM, DDIM, (t % 6) * 128, (t / 6) * 128, tileT32);
        return;
    }
    if (b < 2064) {
        int i = ((b - 1296) * 256 + threadIdx.x) * 8;
        float4 a = *(const float4*)(x + i);
        float4 bb = *(const float4*)(x + i + 4);
        ushort4 lo = make_ushort4(f2bf(a.x), f2bf(a.y), f2bf(a.z), f2bf(a.w));
        ushort4 hi = make_ushort4(f2bf(bb.x), f2bf(bb.y), f2bf(bb.z), f2bf(bb.w));
        *(ushort4*)(xb + i) = lo;
        *(ushort4*)(xb + i + 4) = hi;
        return;
    }
    // ---- router ----
    int lane = threadIdx.x & 63;
    int t = (b - 2064) * 4 + (threadIdx.x >> 6);
    float acc[8];
    #pragma unroll
    for (int e = 0; e < 8; e++) acc[e] = 0.f;
    #pragma unroll
    for (int i = 0; i < 12; i++) {
        int d = i * 64 + lane;
        float xv = x[t * DDIM + d];
        float4 w0 = *(const float4*)(Wr + d * 8);
        float4 w1 = *(const float4*)(Wr + d * 8 + 4);
        acc[0] += xv * w0.x; acc[1] += xv * w0.y; acc[2] += xv * w0.z; acc[3] += xv * w0.w;
        acc[4] += xv * w1.x; acc[5] += xv * w1.y; acc[6] += xv * w1.z; acc[7] += xv * w1.w;
    }
    #pragma unroll
    for (int e = 0; e < 8; e++) {
        #pragma unroll
        for (int off2 = 32; off2 >= 1; off2 >>= 1)
            acc[e] += __shfl_xor(acc[e], off2, 64);
    }
    if (lane == 0) {
        float lg[8];
        #pragma unroll
        for (int e = 0; e < 8; e++) lg[e] = acc[e] + br[e] + 0.1f * noise[t * 8 + e];
        int e0 = 0;
        #pragma unroll
        for (int e = 1; e < 8; e++) if (lg[e] > lg[e0]) e0 = e;
        int e1 = -1;
        #pragma unroll
        for (int e = 0; e < 8; e++) if (e != e0 && (e1 < 0 || lg[e] > lg[e1])) e1 = e;
        float m = fmaxf(lg[e0], lg[e1]);
        float p0 = expf(lg[e0] - m), p1 = expf(lg[e1] - m);
        float inv_s = 1.f / (p0 + p1);
        int s0 = atomicAdd(&counts[e0], 1);
        list[e0 * TNUM + s0] = t;
        int s1 = atomicAdd(&counts[e1], 1);
        list[e1 * TNUM + s1] = t;
        inv[t * 2 + 0] = (e0 << 16) | s0;
        inv[t * 2 + 1] = (e1 << 16) | s1;
        tokp[t * 2 + 0] = p0 * inv_s;
        tokp[t * 2 + 1] = p1 * inv_s;
    }
}

// ---------------- GEMM layer 1 (fused transpose, DEPTH-2 pipeline) ----------------
// R8: the fused B-reg path forced per-step vmcnt(0) drain (B loads and A
// global_load_lds share the counter) -> each K-step exposed a full L2/HBM round
// trip. Now: 2 named B-register sets + 3 A LDS buffers, steady-state WAITVM(6)
// (= 1 tile of 6 VMEM ops in flight); loads get ~2 full steps to land. K-loop
// unrolled x6 (LCM of reg-set and buffer cycles) so all indices compile-time.
// LDS 32KB (3x8 A + 8 B). Numerics identical to R6/R7 ffn1.
#define FFN1_STEP(KIDX, BA, BB, BUF)                                              \
    {                                                                             \
        const int kt_ = (KIDX);                                                   \
        if (kt_ == KT - 1) { WAITVM(0); } else { WAITVM(6); }                     \
        _Pragma("unroll")                                                         \
        for (int p = 0; p < 2; p++) {                                             \
            int kp = p * 8 + rp0;                                                 \
            int gb = ((nlh * 64 + (kp >> 2) * 16 + nll4) << 2) + ((kp + nlh) & 3);\
            float4 pa = BA[p], pb = BB[p];                                        \
            Bs32[gb + 0]  = (unsigned int)f2bf(pa.x) | ((unsigned int)f2bf(pb.x) << 16); \
            Bs32[gb + 4]  = (unsigned int)f2bf(pa.y) | ((unsigned int)f2bf(pb.y) << 16); \
            Bs32[gb + 8]  = (unsigned int)f2bf(pa.z) | ((unsigned int)f2bf(pb.z) << 16); \
            Bs32[gb + 12] = (unsigned int)f2bf(pa.w) | ((unsigned int)f2bf(pb.w) << 16); \
        }                                                                         \
        if (kt_ + 2 < KT) {                                                       \
            int ko = (kt_ + 2) * 32;                                              \
            _Pragma("unroll")                                                     \
            for (int r = 0; r < 2; r++)                                           \
                async_cp16(gA[r] + ko, &As[((BUF) + 2) % 3][ldsoff[r]]);          \
            _Pragma("unroll")                                                     \
            for (int p = 0; p < 2; p++) {                                         \
                const float* bp = Bf + (size_t)(ko + 2 * (p * 8 + rp0)) * HDIM + n0 + c4; \
                BA[p] = *(const float4*)bp;                                       \
                BB[p] = *(const float4*)(bp + HDIM);                              \
            }                                                                     \
        }                                                                         \
        WAITLGKM();                                                               \
        __builtin_amdgcn_s_barrier();                                             \
        MEMFENCE();                                                               \
        bf16x8 af[4], bv[4];                                                      \
        _Pragma("unroll")                                                         \
        for (int i = 0; i < 4; i++)                                               \
            af[i] = *(const bf16x8*)&As[(BUF)][((rcA + i) * 64 + quad * 16 + l15) * 8]; \
        _Pragma("unroll")                                                         \
        for (int jj = 0; jj < 4; jj++) {                                          \
            uint4 Wv = *(const uint4*)&Bs32[((rcB + jj) * 64 + quad * 16 + l15) << 2]; \
            unsigned int s0 = Wv.x, s1 = Wv.y, s2 = Wv.z, s3 = Wv.w;              \
            unsigned int t0, t1, t2, t3;                                          \
            if (jj == 0)      { t0 = s0; t1 = s1; t2 = s2; t3 = s3; }             \
            else if (jj == 1) { t0 = s1; t1 = s2; t2 = s3; t3 = s0; }             \
            else if (jj == 2) { t0 = s2; t1 = s3; t2 = s0; t3 = s1; }             \
            else              { t0 = s3; t1 = s0; t2 = s1; t3 = s2; }             \
            uint4 L; L.x = t0; L.y = t1; L.z = t2; L.w = t3;                      \
            __builtin_memcpy(&bv[jj], &L, 16);                                    \
        }                                                                         \
        _Pragma("unroll")                                                         \
        for (int i = 0; i < 4; i++)                                               \
            _Pragma("unroll")                                                     \
            for (int jj = 0; jj < 4; jj++)                                        \
                acc[i][jj] = __builtin_amdgcn_mfma_f32_16x16x32_bf16(af[i], bv[jj], acc[i][jj], 0, 0, 0); \
        MEMFENCE();                                                               \
        __builtin_amdgcn_s_barrier();                                             \
        MEMFENCE();                                                               \
    }

__global__ __launch_bounds__(256, 3)
void ffn1_kernel(const unsigned short* __restrict__ xb,
                 const float* __restrict__ W1,      // [8][768][3072] f32
                 const float* __restrict__ Ws1,     // [768][3072] f32
                 const float* __restrict__ b1, const float* __restrict__ bs1,
                 const int* __restrict__ counts, const int* __restrict__ list,
                 unsigned short* __restrict__ hbuf) {      // [6144][3072]
    __shared__ __align__(16) unsigned short As[3][512 * 8];   // 3 x 8KB
    __shared__ __align__(16) unsigned int Bs32[2048];         // 8KB

    int j = blockIdx.z * 8 + blockIdx.x;    // 0..39
    int y = blockIdx.y;                     // 0..23
    int mt0 = y / 6, ntl = y % 6;           // mt0 0..3, ntl 0..5

    int offv[8];
    { int s = 0;
      #pragma unroll
      for (int e = 0; e < 8; e++) { offv[e] = s; s += counts[e]; } }

    int cnt, hbase, n0, mbase, ntiles;
    const float* Bf;
    const float* bias;
    const int* lst = nullptr;
    if (j < 32) {
        int e = j >> 2, nq = j & 3;
        cnt = counts[e];
        ntiles = (cnt + 127) >> 7;
        mbase = 0;
        hbase = offv[e];
        n0 = nq * 768 + ntl * 128;
        Bf = W1 + (size_t)e * DDIM * HDIM;
        bias = b1 + e * HDIM;
        lst = list + e * TNUM;
    } else {
        int q = j - 32;                     // 0..7
        int ms = q >> 2, nq = q & 3;
        mbase = ms * 1024;
        ntiles = 8;
        cnt = 1 << 30;
        hbase = 2 * TNUM;
        n0 = nq * 768 + ntl * 128;
        Bf = Ws1;
        bias = bs1;
    }
    if (mt0 >= ntiles) return;

    int tid = threadIdx.x;
    int w = tid >> 6, lane = tid & 63;
    int l15 = lane & 15, quad = lane >> 4;
    int wm = (w & 1) * 64, wn = (w >> 1) * 64;
    int rcA = (w & 1) * 4;
    int rcB = (w >> 1) * 4;
    const int KT = DDIM / 32;   // 24

    int l31 = tid & 31;
    int rp0 = tid >> 5;            // 0..7
    int nlh = l31 >> 2;
    int nll4 = (l31 & 3) * 4;
    int c4 = l31 * 4;

    int ldsoff[2], rowl[2];
    #pragma unroll
    for (int r = 0; r < 2; r++) {
        int rc = r * 4 + w;
        rowl[r] = rc * 16 + l15;
        ldsoff[r] = rc * 512;
    }

    for (int mt = mt0; mt < ntiles; mt += 4) {
        int m0 = mbase + mt * 128;
        const unsigned short* gA[2];
        #pragma unroll
        for (int r = 0; r < 2; r++) {
            int row;
            if (lst) row = lst[min(m0 + rowl[r], cnt - 1)];
            else     row = m0 + rowl[r];
            gA[r] = xb + (size_t)row * DDIM + quad * 8;
        }

        f32x4 zero = {0.f, 0.f, 0.f, 0.f};
        f32x4 acc[4][4];
        #pragma unroll
        for (int i = 0; i < 4; i++)
            #pragma unroll
            for (int jj = 0; jj < 4; jj++) acc[i][jj] = zero;

        float4 Ba0[2], Bb0[2], Ba1[2], Bb1[2];
        // prologue T0 (oldest 6 vmcnt ops)
        #pragma unroll
        for (int r = 0; r < 2; r++) async_cp16(gA[r], &As[0][ldsoff[r]]);
        #pragma unroll
        for (int p = 0; p < 2; p++) {
            const float* bp = Bf + (size_t)(2 * (p * 8 + rp0)) * HDIM + n0 + c4;
            Ba0[p] = *(const float4*)bp;
            Bb0[p] = *(const float4*)(bp + HDIM);
        }
        MEMFENCE();   // pin T0 ops before T1 ops in issue order
        // prologue T1
        #pragma unroll
        for (int r = 0; r < 2; r++) async_cp16(gA[r] + 32, &As[1][ldsoff[r]]);
        #pragma unroll
        for (int p = 0; p < 2; p++) {
            const float* bp = Bf + (size_t)(32 + 2 * (p * 8 + rp0)) * HDIM + n0 + c4;
            Ba1[p] = *(const float4*)bp;
            Bb1[p] = *(const float4*)(bp + HDIM);
        }

        #pragma unroll 1
        for (int kt6 = 0; kt6 < KT; kt6 += 6) {
            FFN1_STEP(kt6 + 0, Ba0, Bb0, 0)
            FFN1_STEP(kt6 + 1, Ba1, Bb1, 1)
            FFN1_STEP(kt6 + 2, Ba0, Bb0, 2)
            FFN1_STEP(kt6 + 3, Ba1, Bb1, 0)
            FFN1_STEP(kt6 + 4, Ba0, Bb0, 1)
            FFN1_STEP(kt6 + 5, Ba1, Bb1, 2)
        }

        #pragma unroll
        for (int i = 0; i < 4; i++) {
            int rbase = m0 + wm + i * 16 + quad * 4;
            #pragma unroll
            for (int jj = 0; jj < 4; jj++) {
                int gc = n0 + wn + jj * 16 + l15;
                float bvl = bias[gc];
                #pragma unroll
                for (int r = 0; r < 4; r++) {
                    int gr = rbase + r;
                    if (gr < cnt) {
                        float v = acc[i][jj][r] + bvl;
                        v = v > 0.f ? v : 0.01f * v;
                        hbuf[(size_t)(hbase + gr) * HDIM + gc] = f2bf(v);
                    }
                }
            }
        }
    }
}

// ---------------- GEMM layer 2 (R7-exact): BM=128, BN=128, BK=32 ----------------
__global__ __launch_bounds__(256, 4)
void ffn2_kernel(const unsigned short* __restrict__ hbuf,
                 const unsigned short* __restrict__ W2t,   // [8][768][3072]
                 const unsigned short* __restrict__ Ws2t,  // [768][3072]
                 const int* __restrict__ counts,
                 float* __restrict__ ybuf) {               // [2][6144][768]
    __shared__ __align__(16) unsigned short As[2][512 * 8];   // 2 x 8KB
    __shared__ __align__(16) unsigned short Bs[2][512 * 8];   // 2 x 8KB (32KB total)

    int j = blockIdx.z * 8 + blockIdx.x;    // 0..23
    int y = blockIdx.y;                     // 0..23
    int mt0 = y / 6, ntl = y % 6;           // mt0 0..3, ntl 0..5
    int n0 = ntl * 128;

    int offv[8];
    { int s = 0;
      #pragma unroll
      for (int e = 0; e < 8; e++) { offv[e] = s; s += counts[e]; } }

    int cnt, hbase, mbase, kh, ntiles;
    const unsigned short* Bmat;
    if (j < 16) {
        int e = j >> 1; kh = j & 1;
        cnt = counts[e];
        ntiles = (cnt + 127) >> 7;
        mbase = 0;
        hbase = offv[e];
        Bmat = W2t + (size_t)e * DDIM * HDIM;
    } else {
        int q = j - 16;
        int ms = q >> 1; kh = q & 1;
        mbase = ms * 512;
        ntiles = 4;
        cnt = 1 << 30;
        hbase = 2 * TNUM;
        Bmat = Ws2t;
    }
    if (mt0 >= ntiles) return;
    int kbase = kh * (HDIM / 2);

    int tid = threadIdx.x;
    int w = tid >> 6, lane = tid & 63;
    int l15 = lane & 15, quad = lane >> 4;
    int wm = (w & 1) * 64, wn = (w >> 1) * 64;
    int rcA = (w & 1) * 4;
    int rcB = (w >> 1) * 4;
    const int KT = (HDIM / 2) / 32;   // 48

    const unsigned short* gB[2];
    int ldsoff[2], rowl[2];
    #pragma unroll
    for (int r = 0; r < 2; r++) {
        int rc = r * 4 + w;
        rowl[r] = rc * 16 + l15;
        ldsoff[r] = rc * 512;
        gB[r] = Bmat + (size_t)(n0 + rowl[r]) * HDIM + kbase + quad * 8;
    }
    float* yb = ybuf + (size_t)kh * 6144 * DDIM;

    for (int mt = mt0; mt < ntiles; mt += 4) {
        int m0 = mbase + mt * 128;
        const unsigned short* gA[2];
        #pragma unroll
        for (int r = 0; r < 2; r++) {
            int row = (j < 16) ? min(m0 + rowl[r], cnt - 1) : (m0 + rowl[r]);
            gA[r] = hbuf + (size_t)(hbase + row) * HDIM + kbase + quad * 8;
        }

        f32x4 zero = {0.f, 0.f, 0.f, 0.f};
        f32x4 acc[4][4];
        #pragma unroll
        for (int i = 0; i < 4; i++)
            #pragma unroll
            for (int jj = 0; jj < 4; jj++) acc[i][jj] = zero;

        // prologue: tiles 0 and 1
        #pragma unroll
        for (int t = 0; t < 2; t++)
            #pragma unroll
            for (int r = 0; r < 2; r++) {
                async_cp16(gA[r] + t * 32, &As[t][ldsoff[r]]);
                async_cp16(gB[r] + t * 32, &Bs[t][ldsoff[r]]);
            }

        #pragma unroll 1
        for (int kt = 0; kt < KT; kt++) {
            if (kt == KT - 1) { WAITVM(0); } else { WAITVM(4); }   // oldest tile arrived
            __builtin_amdgcn_s_barrier();
            MEMFENCE();
            int cur = kt & 1;
            bf16x8 af[4], bv[4];
            #pragma unroll
            for (int i = 0; i < 4; i++)
                af[i] = *(const bf16x8*)&As[cur][((rcA + i) * 64 + quad * 16 + l15) * 8];
            #pragma unroll
            for (int jj = 0; jj < 4; jj++)
                bv[jj] = *(const bf16x8*)&Bs[cur][((rcB + jj) * 64 + quad * 16 + l15) * 8];
            #pragma unroll
            for (int i = 0; i < 4; i++)
                #pragma unroll
                for (int jj = 0; jj < 4; jj++)
                    acc[i][jj] = __builtin_amdgcn_mfma_f32_16x16x32_bf16(af[i], bv[jj], acc[i][jj], 0, 0, 0);
            MEMFENCE();
            __builtin_amdgcn_s_barrier();      // all waves done reading buf[cur]
            MEMFENCE();
            if (kt + 2 < KT) {
                int ko = (kt + 2) * 32;
                #pragma unroll
                for (int r = 0; r < 2; r++) {
                    async_cp16(gA[r] + ko, &As[cur][ldsoff[r]]);
                    async_cp16(gB[r] + ko, &Bs[cur][ldsoff[r]]);
                }
            }
        }

        #pragma unroll
        for (int i = 0; i < 4; i++) {
            int rbase = m0 + wm + i * 16 + quad * 4;
            #pragma unroll
            for (int r = 0; r < 4; r++) {
                int gr = rbase + r;
                if (gr >= cnt) continue;
                float* orow = yb + (size_t)(hbase + gr) * DDIM + n0 + wn;
                #pragma unroll
                for (int jj = 0; jj < 4; jj++)
                    orow[jj * 16 + l15] = acc[i][jj][r];
            }
        }
    }
}

// ---------------- final mix ----------------
__global__ void mix_kernel(const float* __restrict__ ybuf, const int* __restrict__ inv,
                           const float* __restrict__ tokp, const int* __restrict__ counts,
                           const float* __restrict__ b2, const float* __restrict__ bs2,
                           const float* __restrict__ alpha, const float* __restrict__ beta,
                           float* __restrict__ out) {
    int t = blockIdx.x;
    int c = threadIdx.x * 4;
    int offv[8];
    { int s = 0;
      #pragma unroll
      for (int e = 0; e < 8; e++) { offv[e] = s; s += counts[e]; } }
    float a = alpha[0], bsc = beta[0];
    float m = fmaxf(a, bsc);
    float ea = expf(a - m), eb = expf(bsc - m);
    float is = 1.f / (ea + eb);
    float ws = ea * is, wmx = eb * is;

    int i0 = inv[t * 2 + 0], i1 = inv[t * 2 + 1];
    int e0 = i0 >> 16, sl0 = i0 & 0xFFFF;
    int e1 = i1 >> 16, sl1 = i1 & 0xFFFF;
    float p0 = tokp[t * 2 + 0], p1 = tokp[t * 2 + 1];
    size_t rA = (size_t)(offv[e0] + sl0) * DDIM + c;
    size_t rB = (size_t)(offv[e1] + sl1) * DDIM + c;
    size_t rS = (size_t)(2 * TNUM + t) * DDIM + c;
    const float* y0 = ybuf;
    const float* y1 = ybuf + (size_t)6144 * DDIM;
    float4 vA0 = *(const float4*)(y0 + rA);
    float4 vA1 = *(const float4*)(y1 + rA);
    float4 vB0 = *(const float4*)(y0 + rB);
    float4 vB1 = *(const float4*)(y1 + rB);
    float4 vS0 = *(const float4*)(y0 + rS);
    float4 vS1 = *(const float4*)(y1 + rS);
    float4 bA = *(const float4*)(b2 + e0 * DDIM + c);
    float4 bB = *(const float4*)(b2 + e1 * DDIM + c);
    float4 bS = *(const float4*)(bs2 + c);
    float4 o;
    o.x = ws * (vS0.x + vS1.x + bS.x) + wmx * (p0 * (vA0.x + vA1.x + bA.x) + p1 * (vB0.x + vB1.x + bB.x));
    o.y = ws * (vS0.y + vS1.y + bS.y) + wmx * (p0 * (vA0.y + vA1.y + bA.y) + p1 * (vB0.y + vB1.y + bB.y));
    o.z = ws * (vS0.z + vS1.z + bS.z) + wmx * (p0 * (vA0.z + vA1.z + bA.z) + p1 * (vB0.z + vB1.z + bB.z));
    o.w = ws * (vS0.w + vS1.w + bS.w) + wmx * (p0 * (vA0.w + vA1.w + bA.w) + p1 * (vB0.w + vB1.w + bB.w));
    *(float4*)(out + (size_t)t * DDIM + c) = o;
}

extern "C" void kernel_launch(void* const* d_in, const int* in_sizes, int n_in,
                              void* d_out, int out_size, void* d_ws, size_t ws_size,
                              hipStream_t stream) {
    const float* x     = (const float*)d_in[0];
    const float* noise = (const float*)d_in[1];
    const float* Wr    = (const float*)d_in[2];
    const float* br    = (const float*)d_in[3];
    const float* W1    = (const float*)d_in[4];
    const float* b1    = (const float*)d_in[5];
    const float* W2    = (const float*)d_in[6];
    const float* b2    = (const float*)d_in[7];
    const float* Ws1   = (const float*)d_in[8];
    const float* bs1   = (const float*)d_in[9];
    const float* Ws2   = (const float*)d_in[10];
    const float* bs2   = (const float*)d_in[11];
    const float* alpha = (const float*)d_in[12];
    const float* beta  = (const float*)d_in[13];

    char* ws = (char*)d_ws;
    size_t off = 0;
    auto alloc = [&](size_t bytes) -> char* {
        char* p = ws + off;
        off = (off + bytes + 255) & ~(size_t)255;
        return p;
    };
    int*   counts = (int*)  alloc(ENUM * 4);
    int*   list   = (int*)  alloc((size_t)ENUM * TNUM * 4);
    int*   inv    = (int*)  alloc((size_t)TNUM * 2 * 4);
    float* tokp   = (float*)alloc((size_t)TNUM * 2 * 4);
    unsigned short* xb   = (unsigned short*)alloc((size_t)TNUM * DDIM * 2);
    float* ybuf          = (float*)alloc((size_t)2 * 6144 * DDIM * 4);              // 37.75 MB
    unsigned short* W2t  = (unsigned short*)alloc((size_t)ENUM * DDIM * HDIM * 2);  // 36 MB
    unsigned short* Ws2t = (unsigned short*)alloc((size_t)DDIM * HDIM * 2);         // 4.5 MB
    unsigned short* hbuf = (unsigned short*)alloc((size_t)(3 * TNUM) * HDIM * 2);   // 37.75 MB
    if (off > ws_size) {
        fprintf(stderr, "kernel_launch: workspace too small (need %zu, have %zu)\n", off, ws_size);
        return;
    }

    hipMemsetAsync(counts, 0, ENUM * 4, stream);

    // k1: transw(W2,Ws2) + cast + router (1296 + 768 + 512 blocks)
    pre_kernel<<<dim3(2576), dim3(256), 0, stream>>>(x, noise, Wr, br, W2, Ws2,
                                                     W2t, Ws2t, xb, counts, list, inv, tokp);
    // k2: ffn1 fused-transpose depth-2, 40 jobs (z=5), 32KB LDS
    ffn1_kernel<<<dim3(8, 24, 5), dim3(256), 0, stream>>>(xb, W1, Ws1, b1, bs1, counts, list, hbuf);
    // k3: ffn2 BM=128 (R7-exact), 24 jobs, 32KB LDS, 576 blocks
    ffn2_kernel<<<dim3(8, 24, 3), dim3(256), 0, stream>>>(hbuf, W2t, Ws2t, counts, ybuf);
    // k4: mix
    mix_kernel<<<dim3(TNUM), dim3(192), 0, stream>>>(ybuf, inv, tokp, counts, b2, bs2,
                                                     alpha, beta, (float*)d_out);
}

// Round 9
// 444.439 us; speedup vs baseline: 1.0166x; 1.0166x over previous
//
#include <hip/hip_runtime.h>
#include <hip/hip_bf16.h>
#include <cstdio>
#include <cstdint>

#define TNUM 2048
#define DDIM 768
#define HDIM 3072
#define ENUM 8

#define WAITVM(N) asm volatile("s_waitcnt vmcnt(" #N ")" ::: "memory")
#define WAITLGKM() asm volatile("s_waitcnt lgkmcnt(0)" ::: "memory")
#define MEMFENCE() asm volatile("" ::: "memory")

typedef __attribute__((ext_vector_type(8))) __bf16 bf16x8;
typedef __attribute__((ext_vector_type(4))) float f32x4;

__device__ __forceinline__ unsigned short f2bf(float f) {
    __bf16 h = (__bf16)f;            // RNE
    unsigned short u;
    __builtin_memcpy(&u, &h, 2);
    return u;
}

__device__ __forceinline__ void async_cp16(const unsigned short* g, unsigned short* l) {
    __builtin_amdgcn_global_load_lds((const __attribute__((address_space(1))) void*)g,
                                     (__attribute__((address_space(3))) void*)l,
                                     16, 0, 0);
}

// ---------------- 128x128 transpose+cast tile (W2/Ws2 only) ----------------
__device__ __forceinline__ void transpose_tile(const float* __restrict__ in,
                                               unsigned short* __restrict__ out,
                                               int R, int C, int c0, int r0,
                                               unsigned int* tileT32) {
    int tid = threadIdx.x;
    int l15 = tid & 15;
    int g = tid >> 4;
    int par = (g >> 1) & 1;
    int hf = g & 1;
    int cb = hf * 64 + l15 * 4;
    const float* src = in + (size_t)(r0 + (g >> 1)) * C + c0 + cb;
    float4 v[16];
    #pragma unroll
    for (int p = 0; p < 16; p++)
        v[p] = *(const float4*)(src + (size_t)p * 8 * C);
    #pragma unroll
    for (int p = 0; p < 16; p++) {
        int unit = p * 16 + g;
        unsigned int m01 = (unsigned int)f2bf(v[p].x) | ((unsigned int)f2bf(v[p].y) << 16);
        unsigned int m23 = (unsigned int)f2bf(v[p].z) | ((unsigned int)f2bf(v[p].w) << 16);
        unsigned int o01 = __shfl_xor(m01, 32);
        unsigned int o23 = __shfl_xor(m23, 32);
        unsigned int wA = par ? ((o23 & 0xffffu) | (m23 << 16))
                              : ((m01 & 0xffffu) | (o01 << 16));
        unsigned int wB = par ? ((o23 >> 16) | (m23 & 0xffff0000u))
                              : ((m01 >> 16) | (o01 & 0xffff0000u));
        int ca = cb + par * 2;
        int rp = unit >> 2;
        int cq = ca >> 2;
        int woff = 4 * (((rp >> 2) + 3 * cq) & 15) + (((rp & 3) + cq) & 3);
        tileT32[ca * 68 + woff] = wA;
        tileT32[(ca + 1) * 68 + woff] = wB;
    }
    __syncthreads();
    uint4 Wv[8];
    #pragma unroll
    for (int p = 0; p < 8; p++) {
        int cc = p * 16 + g;
        int cqp = cc >> 2;
        Wv[p] = *(const uint4*)&tileT32[cc * 68 + 4 * ((l15 + 3 * cqp) & 15)];
    }
    #pragma unroll
    for (int p = 0; p < 8; p++) {
        int cc = p * 16 + g;
        int cqp = cc >> 2;
        unsigned int a0 = Wv[p].x, a1 = Wv[p].y, a2 = Wv[p].z, a3 = Wv[p].w;
        int rsel = cqp & 3;
        if (rsel & 1) { unsigned int t = a0; a0 = a1; a1 = a2; a2 = a3; a3 = t; }
        if (rsel & 2) { unsigned int t0 = a0, t1 = a1; a0 = a2; a1 = a3; a2 = t0; a3 = t1; }
        uint4 ov; ov.x = a0; ov.y = a1; ov.z = a2; ov.w = a3;
        *(uint4*)(out + (size_t)(c0 + cc) * R + r0 + l15 * 8) = ov;
    }
}

// ---------------- kernel 1: transw(W2,Ws2) || cast_x || router ----------------
__global__ __launch_bounds__(256, 4)
void pre_kernel(const float* __restrict__ x, const float* __restrict__ noise,
                const float* __restrict__ Wr, const float* __restrict__ br,
                const float* __restrict__ W2, const float* __restrict__ Ws2,
                unsigned short* __restrict__ W2t, unsigned short* __restrict__ Ws2t,
                unsigned short* __restrict__ xb,
                int* __restrict__ counts, int* __restrict__ list,
                int* __restrict__ inv, float* __restrict__ tokp) {
    __shared__ __align__(16) unsigned int tileT32[128 * 68];
    int b = blockIdx.x;
    if (b < 1296) {
        int m = b / 144, t = b % 144;   // 9 matrices (W2[0..7], Ws2)
        const float* in     = (m < 8) ? (W2 + (size_t)m * HDIM * DDIM) : Ws2;
        unsigned short* out = (m < 8) ? (W2t + (size_t)m * DDIM * HDIM) : Ws2t;
        transpose_tile(in, out, HDIM, DDIM, (t % 6) * 128, (t / 6) * 128, tileT32);
        return;
    }
    if (b < 2064) {
        int i = ((b - 1296) * 256 + threadIdx.x) * 8;
        float4 a = *(const float4*)(x + i);
        float4 bb = *(const float4*)(x + i + 4);
        ushort4 lo = make_ushort4(f2bf(a.x), f2bf(a.y), f2bf(a.z), f2bf(a.w));
        ushort4 hi = make_ushort4(f2bf(bb.x), f2bf(bb.y), f2bf(bb.z), f2bf(bb.w));
        *(ushort4*)(xb + i) = lo;
        *(ushort4*)(xb + i + 4) = hi;
        return;
    }
    // ---- router ----
    int lane = threadIdx.x & 63;
    int t = (b - 2064) * 4 + (threadIdx.x >> 6);
    float acc[8];
    #pragma unroll
    for (int e = 0; e < 8; e++) acc[e] = 0.f;
    #pragma unroll
    for (int i = 0; i < 12; i++) {
        int d = i * 64 + lane;
        float xv = x[t * DDIM + d];
        float4 w0 = *(const float4*)(Wr + d * 8);
        float4 w1 = *(const float4*)(Wr + d * 8 + 4);
        acc[0] += xv * w0.x; acc[1] += xv * w0.y; acc[2] += xv * w0.z; acc[3] += xv * w0.w;
        acc[4] += xv * w1.x; acc[5] += xv * w1.y; acc[6] += xv * w1.z; acc[7] += xv * w1.w;
    }
    #pragma unroll
    for (int e = 0; e < 8; e++) {
        #pragma unroll
        for (int off2 = 32; off2 >= 1; off2 >>= 1)
            acc[e] += __shfl_xor(acc[e], off2, 64);
    }
    if (lane == 0) {
        float lg[8];
        #pragma unroll
        for (int e = 0; e < 8; e++) lg[e] = acc[e] + br[e] + 0.1f * noise[t * 8 + e];
        int e0 = 0;
        #pragma unroll
        for (int e = 1; e < 8; e++) if (lg[e] > lg[e0]) e0 = e;
        int e1 = -1;
        #pragma unroll
        for (int e = 0; e < 8; e++) if (e != e0 && (e1 < 0 || lg[e] > lg[e1])) e1 = e;
        float m = fmaxf(lg[e0], lg[e1]);
        float p0 = expf(lg[e0] - m), p1 = expf(lg[e1] - m);
        float inv_s = 1.f / (p0 + p1);
        int s0 = atomicAdd(&counts[e0], 1);
        list[e0 * TNUM + s0] = t;
        int s1 = atomicAdd(&counts[e1], 1);
        list[e1 * TNUM + s1] = t;
        inv[t * 2 + 0] = (e0 << 16) | s0;
        inv[t * 2 + 1] = (e1 << 16) | s1;
        tokp[t * 2 + 0] = p0 * inv_s;
        tokp[t * 2 + 1] = p1 * inv_s;
    }
}

// ---------------- GEMM layer 1 (fused transpose, BK=64) ----------------
// R9: R8's depth-2 reverted (L2-residency loss: FETCH/WRITE +50%). Back to the
// proven depth-1 drain-0 scheme but with BK=64: KT 24->12, 32 MFMA/step — the
// per-step fixed cost (exposed latency + 2 barriers) amortizes over 2x work,
// and the longer MFMA phase covers more of the next tile's load latency.
// A: 2 x 16KB LDS buffers (two 8KB k-halves, 4 cp16/thread/step).
// B: single 16KB buffer, 8 float4 loads -> pack both halves (same swizzle per
// half; read rotation by jj unchanged, rcB % 4 == 0). LDS 48KB -> 3 blocks/CU.
// Numerics and k-accumulation order identical to R6/R7.
__global__ __launch_bounds__(256, 3)
void ffn1_kernel(const unsigned short* __restrict__ xb,
                 const float* __restrict__ W1,      // [8][768][3072] f32
                 const float* __restrict__ Ws1,     // [768][3072] f32
                 const float* __restrict__ b1, const float* __restrict__ bs1,
                 const int* __restrict__ counts, const int* __restrict__ list,
                 unsigned short* __restrict__ hbuf) {      // [6144][3072]
    __shared__ __align__(16) unsigned short As[2][1024 * 8];  // 2 x 16KB
    __shared__ __align__(16) unsigned int Bs32[4096];         // 16KB

    int j = blockIdx.z * 8 + blockIdx.x;    // 0..39
    int y = blockIdx.y;                     // 0..23
    int mt0 = y / 6, ntl = y % 6;           // mt0 0..3, ntl 0..5

    int offv[8];
    { int s = 0;
      #pragma unroll
      for (int e = 0; e < 8; e++) { offv[e] = s; s += counts[e]; } }

    int cnt, hbase, n0, mbase, ntiles;
    const float* Bf;
    const float* bias;
    const int* lst = nullptr;
    if (j < 32) {
        int e = j >> 2, nq = j & 3;
        cnt = counts[e];
        ntiles = (cnt + 127) >> 7;
        mbase = 0;
        hbase = offv[e];
        n0 = nq * 768 + ntl * 128;
        Bf = W1 + (size_t)e * DDIM * HDIM;
        bias = b1 + e * HDIM;
        lst = list + e * TNUM;
    } else {
        int q = j - 32;                     // 0..7
        int ms = q >> 2, nq = q & 3;
        mbase = ms * 1024;
        ntiles = 8;
        cnt = 1 << 30;
        hbase = 2 * TNUM;
        n0 = nq * 768 + ntl * 128;
        Bf = Ws1;
        bias = bs1;
    }
    if (mt0 >= ntiles) return;

    int tid = threadIdx.x;
    int w = tid >> 6, lane = tid & 63;
    int l15 = lane & 15, quad = lane >> 4;
    int wm = (w & 1) * 64, wn = (w >> 1) * 64;
    int rcA = (w & 1) * 4;
    int rcB = (w >> 1) * 4;
    const int KT = DDIM / 64;   // 12

    int l31 = tid & 31;
    int rp0 = tid >> 5;            // 0..7
    int nlh = l31 >> 2;
    int nll4 = (l31 & 3) * 4;
    int c4 = l31 * 4;

    int ldsoff[2], rowl[2];
    #pragma unroll
    for (int r = 0; r < 2; r++) {
        int rc = r * 4 + w;
        rowl[r] = rc * 16 + l15;
        ldsoff[r] = rc * 512;
    }

    for (int mt = mt0; mt < ntiles; mt += 4) {
        int m0 = mbase + mt * 128;
        const unsigned short* gA[2];
        #pragma unroll
        for (int r = 0; r < 2; r++) {
            int row;
            if (lst) row = lst[min(m0 + rowl[r], cnt - 1)];
            else     row = m0 + rowl[r];
            gA[r] = xb + (size_t)row * DDIM + quad * 8;
        }

        f32x4 zero = {0.f, 0.f, 0.f, 0.f};
        f32x4 acc[4][4];
        #pragma unroll
        for (int i = 0; i < 4; i++)
            #pragma unroll
            for (int jj = 0; jj < 4; jj++) acc[i][jj] = zero;

        // prologue: A(0) -> As[0] (both halves), B(0) -> regs
        #pragma unroll
        for (int h = 0; h < 2; h++)
            #pragma unroll
            for (int r = 0; r < 2; r++)
                async_cp16(gA[r] + h * 32, &As[0][h * 4096 + ldsoff[r]]);
        float4 Ba[2][2], Bb[2][2];
        #pragma unroll
        for (int h = 0; h < 2; h++)
            #pragma unroll
            for (int p = 0; p < 2; p++) {
                const float* bp = Bf + (size_t)(h * 32 + 2 * (p * 8 + rp0)) * HDIM + n0 + c4;
                Ba[h][p] = *(const float4*)bp;
                Bb[h][p] = *(const float4*)(bp + HDIM);
            }

        #pragma unroll 1
        for (int kt = 0; kt < KT; kt++) {
            int cur = kt & 1;
            WAITVM(0);                 // A(kt) in As[cur]; B(kt) regs ready
            // pack + write B(kt) -> Bs32 (both halves)
            #pragma unroll
            for (int h = 0; h < 2; h++)
                #pragma unroll
                for (int p = 0; p < 2; p++) {
                    int kp = p * 8 + rp0;
                    int gb = h * 2048 + ((nlh * 64 + (kp >> 2) * 16 + nll4) << 2) + ((kp + nlh) & 3);
                    float4 a = Ba[h][p], b = Bb[h][p];
                    Bs32[gb + 0]  = (unsigned int)f2bf(a.x) | ((unsigned int)f2bf(b.x) << 16);
                    Bs32[gb + 4]  = (unsigned int)f2bf(a.y) | ((unsigned int)f2bf(b.y) << 16);
                    Bs32[gb + 8]  = (unsigned int)f2bf(a.z) | ((unsigned int)f2bf(b.z) << 16);
                    Bs32[gb + 12] = (unsigned int)f2bf(a.w) | ((unsigned int)f2bf(b.w) << 16);
                }
            // prefetch tile kt+1 (A -> other LDS buffer, B -> regs)
            if (kt + 1 < KT) {
                int ko = (kt + 1) * 64;
                #pragma unroll
                for (int h = 0; h < 2; h++) {
                    #pragma unroll
                    for (int r = 0; r < 2; r++)
                        async_cp16(gA[r] + ko + h * 32, &As[cur ^ 1][h * 4096 + ldsoff[r]]);
                    #pragma unroll
                    for (int p = 0; p < 2; p++) {
                        const float* bp = Bf + (size_t)(ko + h * 32 + 2 * (p * 8 + rp0)) * HDIM + n0 + c4;
                        Ba[h][p] = *(const float4*)bp;
                        Bb[h][p] = *(const float4*)(bp + HDIM);
                    }
                }
            }
            WAITLGKM();                // my ds_writes complete
            __builtin_amdgcn_s_barrier();
            MEMFENCE();
            #pragma unroll
            for (int h = 0; h < 2; h++) {
                bf16x8 af[4], bv[4];
                #pragma unroll
                for (int i = 0; i < 4; i++)
                    af[i] = *(const bf16x8*)&As[cur][h * 4096 + ((rcA + i) * 64 + quad * 16 + l15) * 8];
                #pragma unroll
                for (int jj = 0; jj < 4; jj++) {
                    uint4 Wv = *(const uint4*)&Bs32[h * 2048 + (((rcB + jj) * 64 + quad * 16 + l15) << 2)];
                    unsigned int s0 = Wv.x, s1 = Wv.y, s2 = Wv.z, s3 = Wv.w;
                    unsigned int t0, t1, t2, t3;
                    if (jj == 0)      { t0 = s0; t1 = s1; t2 = s2; t3 = s3; }
                    else if (jj == 1) { t0 = s1; t1 = s2; t2 = s3; t3 = s0; }
                    else if (jj == 2) { t0 = s2; t1 = s3; t2 = s0; t3 = s1; }
                    else              { t0 = s3; t1 = s0; t2 = s1; t3 = s2; }
                    uint4 L; L.x = t0; L.y = t1; L.z = t2; L.w = t3;
                    __builtin_memcpy(&bv[jj], &L, 16);
                }
                #pragma unroll
                for (int i = 0; i < 4; i++)
                    #pragma unroll
                    for (int jj = 0; jj < 4; jj++)
                        acc[i][jj] = __builtin_amdgcn_mfma_f32_16x16x32_bf16(af[i], bv[jj], acc[i][jj], 0, 0, 0);
            }
            MEMFENCE();
            __builtin_amdgcn_s_barrier();
            MEMFENCE();
        }

        #pragma unroll
        for (int i = 0; i < 4; i++) {
            int rbase = m0 + wm + i * 16 + quad * 4;
            #pragma unroll
            for (int jj = 0; jj < 4; jj++) {
                int gc = n0 + wn + jj * 16 + l15;
                float bvl = bias[gc];
                #pragma unroll
                for (int r = 0; r < 4; r++) {
                    int gr = rbase + r;
                    if (gr < cnt) {
                        float v = acc[i][jj][r] + bvl;
                        v = v > 0.f ? v : 0.01f * v;
                        hbuf[(size_t)(hbase + gr) * HDIM + gc] = f2bf(v);
                    }
                }
            }
        }
    }
}

// ---------------- GEMM layer 2 (R7-exact): BM=128, BN=128, BK=32 ----------------
__global__ __launch_bounds__(256, 4)
void ffn2_kernel(const unsigned short* __restrict__ hbuf,
                 const unsigned short* __restrict__ W2t,   // [8][768][3072]
                 const unsigned short* __restrict__ Ws2t,  // [768][3072]
                 const int* __restrict__ counts,
                 float* __restrict__ ybuf) {               // [2][6144][768]
    __shared__ __align__(16) unsigned short As[2][512 * 8];   // 2 x 8KB
    __shared__ __align__(16) unsigned short Bs[2][512 * 8];   // 2 x 8KB (32KB total)

    int j = blockIdx.z * 8 + blockIdx.x;    // 0..23
    int y = blockIdx.y;                     // 0..23
    int mt0 = y / 6, ntl = y % 6;           // mt0 0..3, ntl 0..5
    int n0 = ntl * 128;

    int offv[8];
    { int s = 0;
      #pragma unroll
      for (int e = 0; e < 8; e++) { offv[e] = s; s += counts[e]; } }

    int cnt, hbase, mbase, kh, ntiles;
    const unsigned short* Bmat;
    if (j < 16) {
        int e = j >> 1; kh = j & 1;
        cnt = counts[e];
        ntiles = (cnt + 127) >> 7;
        mbase = 0;
        hbase = offv[e];
        Bmat = W2t + (size_t)e * DDIM * HDIM;
    } else {
        int q = j - 16;
        int ms = q >> 1; kh = q & 1;
        mbase = ms * 512;
        ntiles = 4;
        cnt = 1 << 30;
        hbase = 2 * TNUM;
        Bmat = Ws2t;
    }
    if (mt0 >= ntiles) return;
    int kbase = kh * (HDIM / 2);

    int tid = threadIdx.x;
    int w = tid >> 6, lane = tid & 63;
    int l15 = lane & 15, quad = lane >> 4;
    int wm = (w & 1) * 64, wn = (w >> 1) * 64;
    int rcA = (w & 1) * 4;
    int rcB = (w >> 1) * 4;
    const int KT = (HDIM / 2) / 32;   // 48

    const unsigned short* gB[2];
    int ldsoff[2], rowl[2];
    #pragma unroll
    for (int r = 0; r < 2; r++) {
        int rc = r * 4 + w;
        rowl[r] = rc * 16 + l15;
        ldsoff[r] = rc * 512;
        gB[r] = Bmat + (size_t)(n0 + rowl[r]) * HDIM + kbase + quad * 8;
    }
    float* yb = ybuf + (size_t)kh * 6144 * DDIM;

    for (int mt = mt0; mt < ntiles; mt += 4) {
        int m0 = mbase + mt * 128;
        const unsigned short* gA[2];
        #pragma unroll
        for (int r = 0; r < 2; r++) {
            int row = (j < 16) ? min(m0 + rowl[r], cnt - 1) : (m0 + rowl[r]);
            gA[r] = hbuf + (size_t)(hbase + row) * HDIM + kbase + quad * 8;
        }

        f32x4 zero = {0.f, 0.f, 0.f, 0.f};
        f32x4 acc[4][4];
        #pragma unroll
        for (int i = 0; i < 4; i++)
            #pragma unroll
            for (int jj = 0; jj < 4; jj++) acc[i][jj] = zero;

        // prologue: tiles 0 and 1
        #pragma unroll
        for (int t = 0; t < 2; t++)
            #pragma unroll
            for (int r = 0; r < 2; r++) {
                async_cp16(gA[r] + t * 32, &As[t][ldsoff[r]]);
                async_cp16(gB[r] + t * 32, &Bs[t][ldsoff[r]]);
            }

        #pragma unroll 1
        for (int kt = 0; kt < KT; kt++) {
            if (kt == KT - 1) { WAITVM(0); } else { WAITVM(4); }   // oldest tile arrived
            __builtin_amdgcn_s_barrier();
            MEMFENCE();
            int cur = kt & 1;
            bf16x8 af[4], bv[4];
            #pragma unroll
            for (int i = 0; i < 4; i++)
                af[i] = *(const bf16x8*)&As[cur][((rcA + i) * 64 + quad * 16 + l15) * 8];
            #pragma unroll
            for (int jj = 0; jj < 4; jj++)
                bv[jj] = *(const bf16x8*)&Bs[cur][((rcB + jj) * 64 + quad * 16 + l15) * 8];
            #pragma unroll
            for (int i = 0; i < 4; i++)
                #pragma unroll
                for (int jj = 0; jj < 4; jj++)
                    acc[i][jj] = __builtin_amdgcn_mfma_f32_16x16x32_bf16(af[i], bv[jj], acc[i][jj], 0, 0, 0);
            MEMFENCE();
            __builtin_amdgcn_s_barrier();      // all waves done reading buf[cur]
            MEMFENCE();
            if (kt + 2 < KT) {
                int ko = (kt + 2) * 32;
                #pragma unroll
                for (int r = 0; r < 2; r++) {
                    async_cp16(gA[r] + ko, &As[cur][ldsoff[r]]);
                    async_cp16(gB[r] + ko, &Bs[cur][ldsoff[r]]);
                }
            }
        }

        #pragma unroll
        for (int i = 0; i < 4; i++) {
            int rbase = m0 + wm + i * 16 + quad * 4;
            #pragma unroll
            for (int r = 0; r < 4; r++) {
                int gr = rbase + r;
                if (gr >= cnt) continue;
                float* orow = yb + (size_t)(hbase + gr) * DDIM + n0 + wn;
                #pragma unroll
                for (int jj = 0; jj < 4; jj++)
                    orow[jj * 16 + l15] = acc[i][jj][r];
            }
        }
    }
}

// ---------------- final mix ----------------
__global__ void mix_kernel(const float* __restrict__ ybuf, const int* __restrict__ inv,
                           const float* __restrict__ tokp, const int* __restrict__ counts,
                           const float* __restrict__ b2, const float* __restrict__ bs2,
                           const float* __restrict__ alpha, const float* __restrict__ beta,
                           float* __restrict__ out) {
    int t = blockIdx.x;
    int c = threadIdx.x * 4;
    int offv[8];
    { int s = 0;
      #pragma unroll
      for (int e = 0; e < 8; e++) { offv[e] = s; s += counts[e]; } }
    float a = alpha[0], bsc = beta[0];
    float m = fmaxf(a, bsc);
    float ea = expf(a - m), eb = expf(bsc - m);
    float is = 1.f / (ea + eb);
    float ws = ea * is, wmx = eb * is;

    int i0 = inv[t * 2 + 0], i1 = inv[t * 2 + 1];
    int e0 = i0 >> 16, sl0 = i0 & 0xFFFF;
    int e1 = i1 >> 16, sl1 = i1 & 0xFFFF;
    float p0 = tokp[t * 2 + 0], p1 = tokp[t * 2 + 1];
    size_t rA = (size_t)(offv[e0] + sl0) * DDIM + c;
    size_t rB = (size_t)(offv[e1] + sl1) * DDIM + c;
    size_t rS = (size_t)(2 * TNUM + t) * DDIM + c;
    const float* y0 = ybuf;
    const float* y1 = ybuf + (size_t)6144 * DDIM;
    float4 vA0 = *(const float4*)(y0 + rA);
    float4 vA1 = *(const float4*)(y1 + rA);
    float4 vB0 = *(const float4*)(y0 + rB);
    float4 vB1 = *(const float4*)(y1 + rB);
    float4 vS0 = *(const float4*)(y0 + rS);
    float4 vS1 = *(const float4*)(y1 + rS);
    float4 bA = *(const float4*)(b2 + e0 * DDIM + c);
    float4 bB = *(const float4*)(b2 + e1 * DDIM + c);
    float4 bS = *(const float4*)(bs2 + c);
    float4 o;
    o.x = ws * (vS0.x + vS1.x + bS.x) + wmx * (p0 * (vA0.x + vA1.x + bA.x) + p1 * (vB0.x + vB1.x + bB.x));
    o.y = ws * (vS0.y + vS1.y + bS.y) + wmx * (p0 * (vA0.y + vA1.y + bA.y) + p1 * (vB0.y + vB1.y + bB.y));
    o.z = ws * (vS0.z + vS1.z + bS.z) + wmx * (p0 * (vA0.z + vA1.z + bA.z) + p1 * (vB0.z + vB1.z + bB.z));
    o.w = ws * (vS0.w + vS1.w + bS.w) + wmx * (p0 * (vA0.w + vA1.w + bA.w) + p1 * (vB0.w + vB1.w + bB.w));
    *(float4*)(out + (size_t)t * DDIM + c) = o;
}

extern "C" void kernel_launch(void* const* d_in, const int* in_sizes, int n_in,
                              void* d_out, int out_size, void* d_ws, size_t ws_size,
                              hipStream_t stream) {
    const float* x     = (const float*)d_in[0];
    const float* noise = (const float*)d_in[1];
    const float* Wr    = (const float*)d_in[2];
    const float* br    = (const float*)d_in[3];
    const float* W1    = (const float*)d_in[4];
    const float* b1    = (const float*)d_in[5];
    const float* W2    = (const float*)d_in[6];
    const float* b2    = (const float*)d_in[7];
    const float* Ws1   = (const float*)d_in[8];
    const float* bs1   = (const float*)d_in[9];
    const float* Ws2   = (const float*)d_in[10];
    const float* bs2   = (const float*)d_in[11];
    const float* alpha = (const float*)d_in[12];
    const float* beta  = (const float*)d_in[13];

    char* ws = (char*)d_ws;
    size_t off = 0;
    auto alloc = [&](size_t bytes) -> char* {
        char* p = ws + off;
        off = (off + bytes + 255) & ~(size_t)255;
        return p;
    };
    int*   counts = (int*)  alloc(ENUM * 4);
    int*   list   = (int*)  alloc((size_t)ENUM * TNUM * 4);
    int*   inv    = (int*)  alloc((size_t)TNUM * 2 * 4);
    float* tokp   = (float*)alloc((size_t)TNUM * 2 * 4);
    unsigned short* xb   = (unsigned short*)alloc((size_t)TNUM * DDIM * 2);
    float* ybuf          = (float*)alloc((size_t)2 * 6144 * DDIM * 4);              // 37.75 MB
    unsigned short* W2t  = (unsigned short*)alloc((size_t)ENUM * DDIM * HDIM * 2);  // 36 MB
    unsigned short* Ws2t = (unsigned short*)alloc((size_t)DDIM * HDIM * 2);         // 4.5 MB
    unsigned short* hbuf = (unsigned short*)alloc((size_t)(3 * TNUM) * HDIM * 2);   // 37.75 MB
    if (off > ws_size) {
        fprintf(stderr, "kernel_launch: workspace too small (need %zu, have %zu)\n", off, ws_size);
        return;
    }

    hipMemsetAsync(counts, 0, ENUM * 4, stream);

    // k1: transw(W2,Ws2) + cast + router (1296 + 768 + 512 blocks)
    pre_kernel<<<dim3(2576), dim3(256), 0, stream>>>(x, noise, Wr, br, W2, Ws2,
                                                     W2t, Ws2t, xb, counts, list, inv, tokp);
    // k2: ffn1 fused-transpose BK=64, 40 jobs (z=5), 48KB LDS
    ffn1_kernel<<<dim3(8, 24, 5), dim3(256), 0, stream>>>(xb, W1, Ws1, b1, bs1, counts, list, hbuf);
    // k3: ffn2 BM=128 (R7-exact), 24 jobs, 32KB LDS, 576 blocks
    ffn2_kernel<<<dim3(8, 24, 3), dim3(256), 0, stream>>>(hbuf, W2t, Ws2t, counts, ybuf);
    // k4: mix
    mix_kernel<<<dim3(TNUM), dim3(192), 0, stream>>>(ybuf, inv, tokp, counts, b2, bs2,
                                                     alpha, beta, (float*)d_out);
}

// Round 10
// 415.812 us; speedup vs baseline: 1.0866x; 1.0688x over previous
//
#include <hip/hip_runtime.h>
#include <hip/hip_bf16.h>
#include <cstdio>
#include <cstdint>

#define TNUM 2048
#define DDIM 768
#define HDIM 3072
#define ENUM 8

#define WAITVM(N) asm volatile("s_waitcnt vmcnt(" #N ")" ::: "memory")
#define WAITLGKM() asm volatile("s_waitcnt lgkmcnt(0)" ::: "memory")
#define MEMFENCE() asm volatile("" ::: "memory")

typedef __attribute__((ext_vector_type(8))) __bf16 bf16x8;
typedef __attribute__((ext_vector_type(4))) float f32x4;

__device__ __forceinline__ unsigned short f2bf(float f) {
    __bf16 h = (__bf16)f;            // RNE
    unsigned short u;
    __builtin_memcpy(&u, &h, 2);
    return u;
}

__device__ __forceinline__ void async_cp16(const unsigned short* g, unsigned short* l) {
    __builtin_amdgcn_global_load_lds((const __attribute__((address_space(1))) void*)g,
                                     (__attribute__((address_space(3))) void*)l,
                                     16, 0, 0);
}

// ---------------- 128x128 transpose+cast tile (W2/Ws2 only) ----------------
__device__ __forceinline__ void transpose_tile(const float* __restrict__ in,
                                               unsigned short* __restrict__ out,
                                               int R, int C, int c0, int r0,
                                               unsigned int* tileT32) {
    int tid = threadIdx.x;
    int l15 = tid & 15;
    int g = tid >> 4;
    int par = (g >> 1) & 1;
    int hf = g & 1;
    int cb = hf * 64 + l15 * 4;
    const float* src = in + (size_t)(r0 + (g >> 1)) * C + c0 + cb;
    float4 v[16];
    #pragma unroll
    for (int p = 0; p < 16; p++)
        v[p] = *(const float4*)(src + (size_t)p * 8 * C);
    #pragma unroll
    for (int p = 0; p < 16; p++) {
        int unit = p * 16 + g;
        unsigned int m01 = (unsigned int)f2bf(v[p].x) | ((unsigned int)f2bf(v[p].y) << 16);
        unsigned int m23 = (unsigned int)f2bf(v[p].z) | ((unsigned int)f2bf(v[p].w) << 16);
        unsigned int o01 = __shfl_xor(m01, 32);
        unsigned int o23 = __shfl_xor(m23, 32);
        unsigned int wA = par ? ((o23 & 0xffffu) | (m23 << 16))
                              : ((m01 & 0xffffu) | (o01 << 16));
        unsigned int wB = par ? ((o23 >> 16) | (m23 & 0xffff0000u))
                              : ((m01 >> 16) | (o01 & 0xffff0000u));
        int ca = cb + par * 2;
        int rp = unit >> 2;
        int cq = ca >> 2;
        int woff = 4 * (((rp >> 2) + 3 * cq) & 15) + (((rp & 3) + cq) & 3);
        tileT32[ca * 68 + woff] = wA;
        tileT32[(ca + 1) * 68 + woff] = wB;
    }
    __syncthreads();
    uint4 Wv[8];
    #pragma unroll
    for (int p = 0; p < 8; p++) {
        int cc = p * 16 + g;
        int cqp = cc >> 2;
        Wv[p] = *(const uint4*)&tileT32[cc * 68 + 4 * ((l15 + 3 * cqp) & 15)];
    }
    #pragma unroll
    for (int p = 0; p < 8; p++) {
        int cc = p * 16 + g;
        int cqp = cc >> 2;
        unsigned int a0 = Wv[p].x, a1 = Wv[p].y, a2 = Wv[p].z, a3 = Wv[p].w;
        int rsel = cqp & 3;
        if (rsel & 1) { unsigned int t = a0; a0 = a1; a1 = a2; a2 = a3; a3 = t; }
        if (rsel & 2) { unsigned int t0 = a0, t1 = a1; a0 = a2; a1 = a3; a2 = t0; a3 = t1; }
        uint4 ov; ov.x = a0; ov.y = a1; ov.z = a2; ov.w = a3;
        *(uint4*)(out + (size_t)(c0 + cc) * R + r0 + l15 * 8) = ov;
    }
}

// ---------------- kernel 1: transw(W2,Ws2) || cast_x || router ----------------
__global__ __launch_bounds__(256, 4)
void pre_kernel(const float* __restrict__ x, const float* __restrict__ noise,
                const float* __restrict__ Wr, const float* __restrict__ br,
                const float* __restrict__ W2, const float* __restrict__ Ws2,
                unsigned short* __restrict__ W2t, unsigned short* __restrict__ Ws2t,
                unsigned short* __restrict__ xb,
                int* __restrict__ counts, int* __restrict__ list,
                int* __restrict__ inv, float* __restrict__ tokp) {
    __shared__ __align__(16) unsigned int tileT32[128 * 68];
    int b = blockIdx.x;
    if (b < 1296) {
        int m = b / 144, t = b % 144;   // 9 matrices (W2[0..7], Ws2)
        const float* in     = (m < 8) ? (W2 + (size_t)m * HDIM * DDIM) : Ws2;
        unsigned short* out = (m < 8) ? (W2t + (size_t)m * DDIM * HDIM) : Ws2t;
        transpose_tile(in, out, HDIM, DDIM, (t % 6) * 128, (t / 6) * 128, tileT32);
        return;
    }
    if (b < 2064) {
        int i = ((b - 1296) * 256 + threadIdx.x) * 8;
        float4 a = *(const float4*)(x + i);
        float4 bb = *(const float4*)(x + i + 4);
        ushort4 lo = make_ushort4(f2bf(a.x), f2bf(a.y), f2bf(a.z), f2bf(a.w));
        ushort4 hi = make_ushort4(f2bf(bb.x), f2bf(bb.y), f2bf(bb.z), f2bf(bb.w));
        *(ushort4*)(xb + i) = lo;
        *(ushort4*)(xb + i + 4) = hi;
        return;
    }
    // ---- router ----
    int lane = threadIdx.x & 63;
    int t = (b - 2064) * 4 + (threadIdx.x >> 6);
    float acc[8];
    #pragma unroll
    for (int e = 0; e < 8; e++) acc[e] = 0.f;
    #pragma unroll
    for (int i = 0; i < 12; i++) {
        int d = i * 64 + lane;
        float xv = x[t * DDIM + d];
        float4 w0 = *(const float4*)(Wr + d * 8);
        float4 w1 = *(const float4*)(Wr + d * 8 + 4);
        acc[0] += xv * w0.x; acc[1] += xv * w0.y; acc[2] += xv * w0.z; acc[3] += xv * w0.w;
        acc[4] += xv * w1.x; acc[5] += xv * w1.y; acc[6] += xv * w1.z; acc[7] += xv * w1.w;
    }
    #pragma unroll
    for (int e = 0; e < 8; e++) {
        #pragma unroll
        for (int off2 = 32; off2 >= 1; off2 >>= 1)
            acc[e] += __shfl_xor(acc[e], off2, 64);
    }
    if (lane == 0) {
        float lg[8];
        #pragma unroll
        for (int e = 0; e < 8; e++) lg[e] = acc[e] + br[e] + 0.1f * noise[t * 8 + e];
        int e0 = 0;
        #pragma unroll
        for (int e = 1; e < 8; e++) if (lg[e] > lg[e0]) e0 = e;
        int e1 = -1;
        #pragma unroll
        for (int e = 0; e < 8; e++) if (e != e0 && (e1 < 0 || lg[e] > lg[e1])) e1 = e;
        float m = fmaxf(lg[e0], lg[e1]);
        float p0 = expf(lg[e0] - m), p1 = expf(lg[e1] - m);
        float inv_s = 1.f / (p0 + p1);
        int s0 = atomicAdd(&counts[e0], 1);
        list[e0 * TNUM + s0] = t;
        int s1 = atomicAdd(&counts[e1], 1);
        list[e1 * TNUM + s1] = t;
        inv[t * 2 + 0] = (e0 << 16) | s0;
        inv[t * 2 + 1] = (e1 << 16) | s1;
        tokp[t * 2 + 0] = p0 * inv_s;
        tokp[t * 2 + 1] = p1 * inv_s;
    }
}

// ---------------- GEMM layer 1 (fused transpose, R7-exact pipeline, BALANCED jobs) ----
// R10: R9's BK=64 reverted (traffic amplification again; R7's 24KB config is the
// L2-residency optimum). Single change vs R7: shared expert split 8 -> 16 jobs
// (ms 0..3 x nq 0..3, 512-row slabs), grid z 5 -> 6. Every block now does exactly
// ONE 128x128 m-tile (24 K-steps) — removes the 2x-length shared-block tail that
// set R7's makespan. Per-job working set and per-block LDS/VGPR unchanged.
__global__ __launch_bounds__(256, 3)
void ffn1_kernel(const unsigned short* __restrict__ xb,
                 const float* __restrict__ W1,      // [8][768][3072] f32
                 const float* __restrict__ Ws1,     // [768][3072] f32
                 const float* __restrict__ b1, const float* __restrict__ bs1,
                 const int* __restrict__ counts, const int* __restrict__ list,
                 unsigned short* __restrict__ hbuf) {      // [6144][3072]
    __shared__ __align__(16) unsigned short As[2][512 * 8];   // 2 x 8KB
    __shared__ __align__(16) unsigned int Bs32[2048];         // 8KB

    int j = blockIdx.z * 8 + blockIdx.x;    // 0..47
    int y = blockIdx.y;                     // 0..23
    int mt0 = y / 6, ntl = y % 6;           // mt0 0..3, ntl 0..5

    int offv[8];
    { int s = 0;
      #pragma unroll
      for (int e = 0; e < 8; e++) { offv[e] = s; s += counts[e]; } }

    int cnt, hbase, n0, mbase, ntiles;
    const float* Bf;
    const float* bias;
    const int* lst = nullptr;
    if (j < 32) {
        int e = j >> 2, nq = j & 3;
        cnt = counts[e];
        ntiles = (cnt + 127) >> 7;
        mbase = 0;
        hbase = offv[e];
        n0 = nq * 768 + ntl * 128;
        Bf = W1 + (size_t)e * DDIM * HDIM;
        bias = b1 + e * HDIM;
        lst = list + e * TNUM;
    } else {
        int q = j - 32;                     // 0..15
        int ms = q >> 2, nq = q & 3;        // 4 slabs x 4 col-quarters
        mbase = ms * 512;
        ntiles = 4;
        cnt = 1 << 30;
        hbase = 2 * TNUM;
        n0 = nq * 768 + ntl * 128;
        Bf = Ws1;
        bias = bs1;
    }
    if (mt0 >= ntiles) return;

    int tid = threadIdx.x;
    int w = tid >> 6, lane = tid & 63;
    int l15 = lane & 15, quad = lane >> 4;
    int wm = (w & 1) * 64, wn = (w >> 1) * 64;
    int rcA = (w & 1) * 4;
    int rcB = (w >> 1) * 4;
    const int KT = DDIM / 32;   // 24

    int l31 = tid & 31;
    int rp0 = tid >> 5;            // 0..7
    int nlh = l31 >> 2;
    int nll4 = (l31 & 3) * 4;
    int c4 = l31 * 4;

    int ldsoff[2], rowl[2];
    #pragma unroll
    for (int r = 0; r < 2; r++) {
        int rc = r * 4 + w;
        rowl[r] = rc * 16 + l15;
        ldsoff[r] = rc * 512;
    }

    for (int mt = mt0; mt < ntiles; mt += 4) {
        int m0 = mbase + mt * 128;
        const unsigned short* gA[2];
        #pragma unroll
        for (int r = 0; r < 2; r++) {
            int row;
            if (lst) row = lst[min(m0 + rowl[r], cnt - 1)];
            else     row = m0 + rowl[r];
            gA[r] = xb + (size_t)row * DDIM + quad * 8;
        }

        f32x4 zero = {0.f, 0.f, 0.f, 0.f};
        f32x4 acc[4][4];
        #pragma unroll
        for (int i = 0; i < 4; i++)
            #pragma unroll
            for (int jj = 0; jj < 4; jj++) acc[i][jj] = zero;

        // prologue: issue A tile0 -> As[0]; load B tile0 into regs
        #pragma unroll
        for (int r = 0; r < 2; r++) async_cp16(gA[r], &As[0][ldsoff[r]]);
        float4 Ba[2], Bb[2];
        #pragma unroll
        for (int p = 0; p < 2; p++) {
            const float* bp = Bf + (size_t)(2 * (p * 8 + rp0)) * HDIM + n0 + c4;
            Ba[p] = *(const float4*)bp;
            Bb[p] = *(const float4*)(bp + HDIM);
        }

        #pragma unroll 1
        for (int kt = 0; kt < KT; kt++) {
            int cur = kt & 1;
            WAITVM(0);                 // A(kt) landed in As[cur]; B-regs(kt) ready
            // pack + write B(kt) -> Bs32 (single buffer; lockstep-safe)
            #pragma unroll
            for (int p = 0; p < 2; p++) {
                int kp = p * 8 + rp0;
                int gb = ((nlh * 64 + (kp >> 2) * 16 + nll4) << 2) + ((kp + nlh) & 3);
                float4 a = Ba[p], b = Bb[p];
                Bs32[gb + 0]  = (unsigned int)f2bf(a.x) | ((unsigned int)f2bf(b.x) << 16);
                Bs32[gb + 4]  = (unsigned int)f2bf(a.y) | ((unsigned int)f2bf(b.y) << 16);
                Bs32[gb + 8]  = (unsigned int)f2bf(a.z) | ((unsigned int)f2bf(b.z) << 16);
                Bs32[gb + 12] = (unsigned int)f2bf(a.w) | ((unsigned int)f2bf(b.w) << 16);
            }
            // prefetch tile kt+1 (A -> other LDS buffer, B -> regs)
            if (kt + 1 < KT) {
                int ko = (kt + 1) * 32;
                #pragma unroll
                for (int r = 0; r < 2; r++)
                    async_cp16(gA[r] + ko, &As[cur ^ 1][ldsoff[r]]);
                #pragma unroll
                for (int p = 0; p < 2; p++) {
                    const float* bp = Bf + (size_t)(ko + 2 * (p * 8 + rp0)) * HDIM + n0 + c4;
                    Ba[p] = *(const float4*)bp;
                    Bb[p] = *(const float4*)(bp + HDIM);
                }
            }
            WAITLGKM();                // my ds_writes complete
            __builtin_amdgcn_s_barrier();
            MEMFENCE();
            bf16x8 af[4], bv[4];
            #pragma unroll
            for (int i = 0; i < 4; i++)
                af[i] = *(const bf16x8*)&As[cur][((rcA + i) * 64 + quad * 16 + l15) * 8];
            #pragma unroll
            for (int jj = 0; jj < 4; jj++) {
                uint4 Wv = *(const uint4*)&Bs32[((rcB + jj) * 64 + quad * 16 + l15) << 2];
                unsigned int s0 = Wv.x, s1 = Wv.y, s2 = Wv.z, s3 = Wv.w;
                unsigned int t0, t1, t2, t3;
                if (jj == 0)      { t0 = s0; t1 = s1; t2 = s2; t3 = s3; }
                else if (jj == 1) { t0 = s1; t1 = s2; t2 = s3; t3 = s0; }
                else if (jj == 2) { t0 = s2; t1 = s3; t2 = s0; t3 = s1; }
                else              { t0 = s3; t1 = s0; t2 = s1; t3 = s2; }
                uint4 L; L.x = t0; L.y = t1; L.z = t2; L.w = t3;
                __builtin_memcpy(&bv[jj], &L, 16);
            }
            #pragma unroll
            for (int i = 0; i < 4; i++)
                #pragma unroll
                for (int jj = 0; jj < 4; jj++)
                    acc[i][jj] = __builtin_amdgcn_mfma_f32_16x16x32_bf16(af[i], bv[jj], acc[i][jj], 0, 0, 0);
            MEMFENCE();
            __builtin_amdgcn_s_barrier();
            MEMFENCE();
        }

        #pragma unroll
        for (int i = 0; i < 4; i++) {
            int rbase = m0 + wm + i * 16 + quad * 4;
            #pragma unroll
            for (int jj = 0; jj < 4; jj++) {
                int gc = n0 + wn + jj * 16 + l15;
                float bvl = bias[gc];
                #pragma unroll
                for (int r = 0; r < 4; r++) {
                    int gr = rbase + r;
                    if (gr < cnt) {
                        float v = acc[i][jj][r] + bvl;
                        v = v > 0.f ? v : 0.01f * v;
                        hbuf[(size_t)(hbase + gr) * HDIM + gc] = f2bf(v);
                    }
                }
            }
        }
    }
}

// ---------------- GEMM layer 2 (R7-exact): BM=128, BN=128, BK=32 ----------------
__global__ __launch_bounds__(256, 4)
void ffn2_kernel(const unsigned short* __restrict__ hbuf,
                 const unsigned short* __restrict__ W2t,   // [8][768][3072]
                 const unsigned short* __restrict__ Ws2t,  // [768][3072]
                 const int* __restrict__ counts,
                 float* __restrict__ ybuf) {               // [2][6144][768]
    __shared__ __align__(16) unsigned short As[2][512 * 8];   // 2 x 8KB
    __shared__ __align__(16) unsigned short Bs[2][512 * 8];   // 2 x 8KB (32KB total)

    int j = blockIdx.z * 8 + blockIdx.x;    // 0..23
    int y = blockIdx.y;                     // 0..23
    int mt0 = y / 6, ntl = y % 6;           // mt0 0..3, ntl 0..5
    int n0 = ntl * 128;

    int offv[8];
    { int s = 0;
      #pragma unroll
      for (int e = 0; e < 8; e++) { offv[e] = s; s += counts[e]; } }

    int cnt, hbase, mbase, kh, ntiles;
    const unsigned short* Bmat;
    if (j < 16) {
        int e = j >> 1; kh = j & 1;
        cnt = counts[e];
        ntiles = (cnt + 127) >> 7;
        mbase = 0;
        hbase = offv[e];
        Bmat = W2t + (size_t)e * DDIM * HDIM;
    } else {
        int q = j - 16;
        int ms = q >> 1; kh = q & 1;
        mbase = ms * 512;
        ntiles = 4;
        cnt = 1 << 30;
        hbase = 2 * TNUM;
        Bmat = Ws2t;
    }
    if (mt0 >= ntiles) return;
    int kbase = kh * (HDIM / 2);

    int tid = threadIdx.x;
    int w = tid >> 6, lane = tid & 63;
    int l15 = lane & 15, quad = lane >> 4;
    int wm = (w & 1) * 64, wn = (w >> 1) * 64;
    int rcA = (w & 1) * 4;
    int rcB = (w >> 1) * 4;
    const int KT = (HDIM / 2) / 32;   // 48

    const unsigned short* gB[2];
    int ldsoff[2], rowl[2];
    #pragma unroll
    for (int r = 0; r < 2; r++) {
        int rc = r * 4 + w;
        rowl[r] = rc * 16 + l15;
        ldsoff[r] = rc * 512;
        gB[r] = Bmat + (size_t)(n0 + rowl[r]) * HDIM + kbase + quad * 8;
    }
    float* yb = ybuf + (size_t)kh * 6144 * DDIM;

    for (int mt = mt0; mt < ntiles; mt += 4) {
        int m0 = mbase + mt * 128;
        const unsigned short* gA[2];
        #pragma unroll
        for (int r = 0; r < 2; r++) {
            int row = (j < 16) ? min(m0 + rowl[r], cnt - 1) : (m0 + rowl[r]);
            gA[r] = hbuf + (size_t)(hbase + row) * HDIM + kbase + quad * 8;
        }

        f32x4 zero = {0.f, 0.f, 0.f, 0.f};
        f32x4 acc[4][4];
        #pragma unroll
        for (int i = 0; i < 4; i++)
            #pragma unroll
            for (int jj = 0; jj < 4; jj++) acc[i][jj] = zero;

        // prologue: tiles 0 and 1
        #pragma unroll
        for (int t = 0; t < 2; t++)
            #pragma unroll
            for (int r = 0; r < 2; r++) {
                async_cp16(gA[r] + t * 32, &As[t][ldsoff[r]]);
                async_cp16(gB[r] + t * 32, &Bs[t][ldsoff[r]]);
            }

        #pragma unroll 1
        for (int kt = 0; kt < KT; kt++) {
            if (kt == KT - 1) { WAITVM(0); } else { WAITVM(4); }   // oldest tile arrived
            __builtin_amdgcn_s_barrier();
            MEMFENCE();
            int cur = kt & 1;
            bf16x8 af[4], bv[4];
            #pragma unroll
            for (int i = 0; i < 4; i++)
                af[i] = *(const bf16x8*)&As[cur][((rcA + i) * 64 + quad * 16 + l15) * 8];
            #pragma unroll
            for (int jj = 0; jj < 4; jj++)
                bv[jj] = *(const bf16x8*)&Bs[cur][((rcB + jj) * 64 + quad * 16 + l15) * 8];
            #pragma unroll
            for (int i = 0; i < 4; i++)
                #pragma unroll
                for (int jj = 0; jj < 4; jj++)
                    acc[i][jj] = __builtin_amdgcn_mfma_f32_16x16x32_bf16(af[i], bv[jj], acc[i][jj], 0, 0, 0);
            MEMFENCE();
            __builtin_amdgcn_s_barrier();      // all waves done reading buf[cur]
            MEMFENCE();
            if (kt + 2 < KT) {
                int ko = (kt + 2) * 32;
                #pragma unroll
                for (int r = 0; r < 2; r++) {
                    async_cp16(gA[r] + ko, &As[cur][ldsoff[r]]);
                    async_cp16(gB[r] + ko, &Bs[cur][ldsoff[r]]);
                }
            }
        }

        #pragma unroll
        for (int i = 0; i < 4; i++) {
            int rbase = m0 + wm + i * 16 + quad * 4;
            #pragma unroll
            for (int r = 0; r < 4; r++) {
                int gr = rbase + r;
                if (gr >= cnt) continue;
                float* orow = yb + (size_t)(hbase + gr) * DDIM + n0 + wn;
                #pragma unroll
                for (int jj = 0; jj < 4; jj++)
                    orow[jj * 16 + l15] = acc[i][jj][r];
            }
        }
    }
}

// ---------------- final mix ----------------
__global__ void mix_kernel(const float* __restrict__ ybuf, const int* __restrict__ inv,
                           const float* __restrict__ tokp, const int* __restrict__ counts,
                           const float* __restrict__ b2, const float* __restrict__ bs2,
                           const float* __restrict__ alpha, const float* __restrict__ beta,
                           float* __restrict__ out) {
    int t = blockIdx.x;
    int c = threadIdx.x * 4;
    int offv[8];
    { int s = 0;
      #pragma unroll
      for (int e = 0; e < 8; e++) { offv[e] = s; s += counts[e]; } }
    float a = alpha[0], bsc = beta[0];
    float m = fmaxf(a, bsc);
    float ea = expf(a - m), eb = expf(bsc - m);
    float is = 1.f / (ea + eb);
    float ws = ea * is, wmx = eb * is;

    int i0 = inv[t * 2 + 0], i1 = inv[t * 2 + 1];
    int e0 = i0 >> 16, sl0 = i0 & 0xFFFF;
    int e1 = i1 >> 16, sl1 = i1 & 0xFFFF;
    float p0 = tokp[t * 2 + 0], p1 = tokp[t * 2 + 1];
    size_t rA = (size_t)(offv[e0] + sl0) * DDIM + c;
    size_t rB = (size_t)(offv[e1] + sl1) * DDIM + c;
    size_t rS = (size_t)(2 * TNUM + t) * DDIM + c;
    const float* y0 = ybuf;
    const float* y1 = ybuf + (size_t)6144 * DDIM;
    float4 vA0 = *(const float4*)(y0 + rA);
    float4 vA1 = *(const float4*)(y1 + rA);
    float4 vB0 = *(const float4*)(y0 + rB);
    float4 vB1 = *(const float4*)(y1 + rB);
    float4 vS0 = *(const float4*)(y0 + rS);
    float4 vS1 = *(const float4*)(y1 + rS);
    float4 bA = *(const float4*)(b2 + e0 * DDIM + c);
    float4 bB = *(const float4*)(b2 + e1 * DDIM + c);
    float4 bS = *(const float4*)(bs2 + c);
    float4 o;
    o.x = ws * (vS0.x + vS1.x + bS.x) + wmx * (p0 * (vA0.x + vA1.x + bA.x) + p1 * (vB0.x + vB1.x + bB.x));
    o.y = ws * (vS0.y + vS1.y + bS.y) + wmx * (p0 * (vA0.y + vA1.y + bA.y) + p1 * (vB0.y + vB1.y + bB.y));
    o.z = ws * (vS0.z + vS1.z + bS.z) + wmx * (p0 * (vA0.z + vA1.z + bA.z) + p1 * (vB0.z + vB1.z + bB.z));
    o.w = ws * (vS0.w + vS1.w + bS.w) + wmx * (p0 * (vA0.w + vA1.w + bA.w) + p1 * (vB0.w + vB1.w + bB.w));
    *(float4*)(out + (size_t)t * DDIM + c) = o;
}

extern "C" void kernel_launch(void* const* d_in, const int* in_sizes, int n_in,
                              void* d_out, int out_size, void* d_ws, size_t ws_size,
                              hipStream_t stream) {
    const float* x     = (const float*)d_in[0];
    const float* noise = (const float*)d_in[1];
    const float* Wr    = (const float*)d_in[2];
    const float* br    = (const float*)d_in[3];
    const float* W1    = (const float*)d_in[4];
    const float* b1    = (const float*)d_in[5];
    const float* W2    = (const float*)d_in[6];
    const float* b2    = (const float*)d_in[7];
    const float* Ws1   = (const float*)d_in[8];
    const float* bs1   = (const float*)d_in[9];
    const float* Ws2   = (const float*)d_in[10];
    const float* bs2   = (const float*)d_in[11];
    const float* alpha = (const float*)d_in[12];
    const float* beta  = (const float*)d_in[13];

    char* ws = (char*)d_ws;
    size_t off = 0;
    auto alloc = [&](size_t bytes) -> char* {
        char* p = ws + off;
        off = (off + bytes + 255) & ~(size_t)255;
        return p;
    };
    int*   counts = (int*)  alloc(ENUM * 4);
    int*   list   = (int*)  alloc((size_t)ENUM * TNUM * 4);
    int*   inv    = (int*)  alloc((size_t)TNUM * 2 * 4);
    float* tokp   = (float*)alloc((size_t)TNUM * 2 * 4);
    unsigned short* xb   = (unsigned short*)alloc((size_t)TNUM * DDIM * 2);
    float* ybuf          = (float*)alloc((size_t)2 * 6144 * DDIM * 4);              // 37.75 MB
    unsigned short* W2t  = (unsigned short*)alloc((size_t)ENUM * DDIM * HDIM * 2);  // 36 MB
    unsigned short* Ws2t = (unsigned short*)alloc((size_t)DDIM * HDIM * 2);         // 4.5 MB
    unsigned short* hbuf = (unsigned short*)alloc((size_t)(3 * TNUM) * HDIM * 2);   // 37.75 MB
    if (off > ws_size) {
        fprintf(stderr, "kernel_launch: workspace too small (need %zu, have %zu)\n", off, ws_size);
        return;
    }

    hipMemsetAsync(counts, 0, ENUM * 4, stream);

    // k1: transw(W2,Ws2) + cast + router (1296 + 768 + 512 blocks)
    pre_kernel<<<dim3(2576), dim3(256), 0, stream>>>(x, noise, Wr, br, W2, Ws2,
                                                     W2t, Ws2t, xb, counts, list, inv, tokp);
    // k2: ffn1 fused-transpose (R7 pipeline), 48 balanced jobs (z=6), 24KB LDS
    ffn1_kernel<<<dim3(8, 24, 6), dim3(256), 0, stream>>>(xb, W1, Ws1, b1, bs1, counts, list, hbuf);
    // k3: ffn2 BM=128 (R7-exact), 24 jobs, 32KB LDS, 576 blocks
    ffn2_kernel<<<dim3(8, 24, 3), dim3(256), 0, stream>>>(hbuf, W2t, Ws2t, counts, ybuf);
    // k4: mix
    mix_kernel<<<dim3(TNUM), dim3(192), 0, stream>>>(ybuf, inv, tokp, counts, b2, bs2,
                                                     alpha, beta, (float*)d_out);
}

// Round 11
// 411.484 us; speedup vs baseline: 1.0980x; 1.0105x over previous
//
#include <hip/hip_runtime.h>
#include <hip/hip_bf16.h>
#include <cstdio>
#include <cstdint>

#define TNUM 2048
#define DDIM 768
#define HDIM 3072
#define ENUM 8

#define WAITVM(N) asm volatile("s_waitcnt vmcnt(" #N ")" ::: "memory")
#define WAITLGKM() asm volatile("s_waitcnt lgkmcnt(0)" ::: "memory")
#define MEMFENCE() asm volatile("" ::: "memory")

typedef __attribute__((ext_vector_type(8))) __bf16 bf16x8;
typedef __attribute__((ext_vector_type(4))) float f32x4;

__device__ __forceinline__ unsigned short f2bf(float f) {
    __bf16 h = (__bf16)f;            // RNE
    unsigned short u;
    __builtin_memcpy(&u, &h, 2);
    return u;
}

__device__ __forceinline__ void async_cp16(const unsigned short* g, unsigned short* l) {
    __builtin_amdgcn_global_load_lds((const __attribute__((address_space(1))) void*)g,
                                     (__attribute__((address_space(3))) void*)l,
                                     16, 0, 0);
}

// ---------------- 128x128 transpose+cast tile (W2/Ws2 only) ----------------
__device__ __forceinline__ void transpose_tile(const float* __restrict__ in,
                                               unsigned short* __restrict__ out,
                                               int R, int C, int c0, int r0,
                                               unsigned int* tileT32) {
    int tid = threadIdx.x;
    int l15 = tid & 15;
    int g = tid >> 4;
    int par = (g >> 1) & 1;
    int hf = g & 1;
    int cb = hf * 64 + l15 * 4;
    const float* src = in + (size_t)(r0 + (g >> 1)) * C + c0 + cb;
    float4 v[16];
    #pragma unroll
    for (int p = 0; p < 16; p++)
        v[p] = *(const float4*)(src + (size_t)p * 8 * C);
    #pragma unroll
    for (int p = 0; p < 16; p++) {
        int unit = p * 16 + g;
        unsigned int m01 = (unsigned int)f2bf(v[p].x) | ((unsigned int)f2bf(v[p].y) << 16);
        unsigned int m23 = (unsigned int)f2bf(v[p].z) | ((unsigned int)f2bf(v[p].w) << 16);
        unsigned int o01 = __shfl_xor(m01, 32);
        unsigned int o23 = __shfl_xor(m23, 32);
        unsigned int wA = par ? ((o23 & 0xffffu) | (m23 << 16))
                              : ((m01 & 0xffffu) | (o01 << 16));
        unsigned int wB = par ? ((o23 >> 16) | (m23 & 0xffff0000u))
                              : ((m01 >> 16) | (o01 & 0xffff0000u));
        int ca = cb + par * 2;
        int rp = unit >> 2;
        int cq = ca >> 2;
        int woff = 4 * (((rp >> 2) + 3 * cq) & 15) + (((rp & 3) + cq) & 3);
        tileT32[ca * 68 + woff] = wA;
        tileT32[(ca + 1) * 68 + woff] = wB;
    }
    __syncthreads();
    uint4 Wv[8];
    #pragma unroll
    for (int p = 0; p < 8; p++) {
        int cc = p * 16 + g;
        int cqp = cc >> 2;
        Wv[p] = *(const uint4*)&tileT32[cc * 68 + 4 * ((l15 + 3 * cqp) & 15)];
    }
    #pragma unroll
    for (int p = 0; p < 8; p++) {
        int cc = p * 16 + g;
        int cqp = cc >> 2;
        unsigned int a0 = Wv[p].x, a1 = Wv[p].y, a2 = Wv[p].z, a3 = Wv[p].w;
        int rsel = cqp & 3;
        if (rsel & 1) { unsigned int t = a0; a0 = a1; a1 = a2; a2 = a3; a3 = t; }
        if (rsel & 2) { unsigned int t0 = a0, t1 = a1; a0 = a2; a1 = a3; a2 = t0; a3 = t1; }
        uint4 ov; ov.x = a0; ov.y = a1; ov.z = a2; ov.w = a3;
        *(uint4*)(out + (size_t)(c0 + cc) * R + r0 + l15 * 8) = ov;
    }
}

// ---------------- kernel 1: transw(W2,Ws2) || cast_x || router ----------------
__global__ __launch_bounds__(256, 4)
void pre_kernel(const float* __restrict__ x, const float* __restrict__ noise,
                const float* __restrict__ Wr, const float* __restrict__ br,
                const float* __restrict__ W2, const float* __restrict__ Ws2,
                unsigned short* __restrict__ W2t, unsigned short* __restrict__ Ws2t,
                unsigned short* __restrict__ xb,
                int* __restrict__ counts, int* __restrict__ list,
                int* __restrict__ inv, float* __restrict__ tokp) {
    __shared__ __align__(16) unsigned int tileT32[128 * 68];
    int b = blockIdx.x;
    if (b < 1296) {
        int m = b / 144, t = b % 144;   // 9 matrices (W2[0..7], Ws2)
        const float* in     = (m < 8) ? (W2 + (size_t)m * HDIM * DDIM) : Ws2;
        unsigned short* out = (m < 8) ? (W2t + (size_t)m * DDIM * HDIM) : Ws2t;
        transpose_tile(in, out, HDIM, DDIM, (t % 6) * 128, (t / 6) * 128, tileT32);
        return;
    }
    if (b < 2064) {
        int i = ((b - 1296) * 256 + threadIdx.x) * 8;
        float4 a = *(const float4*)(x + i);
        float4 bb = *(const float4*)(x + i + 4);
        ushort4 lo = make_ushort4(f2bf(a.x), f2bf(a.y), f2bf(a.z), f2bf(a.w));
        ushort4 hi = make_ushort4(f2bf(bb.x), f2bf(bb.y), f2bf(bb.z), f2bf(bb.w));
        *(ushort4*)(xb + i) = lo;
        *(ushort4*)(xb + i + 4) = hi;
        return;
    }
    // ---- router ----
    int lane = threadIdx.x & 63;
    int t = (b - 2064) * 4 + (threadIdx.x >> 6);
    float acc[8];
    #pragma unroll
    for (int e = 0; e < 8; e++) acc[e] = 0.f;
    #pragma unroll
    for (int i = 0; i < 12; i++) {
        int d = i * 64 + lane;
        float xv = x[t * DDIM + d];
        float4 w0 = *(const float4*)(Wr + d * 8);
        float4 w1 = *(const float4*)(Wr + d * 8 + 4);
        acc[0] += xv * w0.x; acc[1] += xv * w0.y; acc[2] += xv * w0.z; acc[3] += xv * w0.w;
        acc[4] += xv * w1.x; acc[5] += xv * w1.y; acc[6] += xv * w1.z; acc[7] += xv * w1.w;
    }
    #pragma unroll
    for (int e = 0; e < 8; e++) {
        #pragma unroll
        for (int off2 = 32; off2 >= 1; off2 >>= 1)
            acc[e] += __shfl_xor(acc[e], off2, 64);
    }
    if (lane == 0) {
        float lg[8];
        #pragma unroll
        for (int e = 0; e < 8; e++) lg[e] = acc[e] + br[e] + 0.1f * noise[t * 8 + e];
        int e0 = 0;
        #pragma unroll
        for (int e = 1; e < 8; e++) if (lg[e] > lg[e0]) e0 = e;
        int e1 = -1;
        #pragma unroll
        for (int e = 0; e < 8; e++) if (e != e0 && (e1 < 0 || lg[e] > lg[e1])) e1 = e;
        float m = fmaxf(lg[e0], lg[e1]);
        float p0 = expf(lg[e0] - m), p1 = expf(lg[e1] - m);
        float inv_s = 1.f / (p0 + p1);
        int s0 = atomicAdd(&counts[e0], 1);
        list[e0 * TNUM + s0] = t;
        int s1 = atomicAdd(&counts[e1], 1);
        list[e1 * TNUM + s1] = t;
        inv[t * 2 + 0] = (e0 << 16) | s0;
        inv[t * 2 + 1] = (e1 << 16) | s1;
        tokp[t * 2 + 0] = p0 * inv_s;
        tokp[t * 2 + 1] = p1 * inv_s;
    }
}

// ---------------- GEMM layer 1 (fused transpose, split-wait pipeline) ----------------
// R11: same one-tile-ahead in-flight state as R10 (no widening — R8/R9 lesson),
// but waits split via issue ORDER (vmcnt retires in order): each step issues
// B(kt+2) reg-loads BEFORE A(kt+1) cp16. Then:
//   top of step:  WAITVM(2)  -> B(kt+1) regs ready (A(kt) still in flight);
//                 pack B(kt+1) -> Bs[kt+1 & 1]   (overlaps A(kt)'s flight)
//   pre-barrier:  WAITVM(6)  -> A(kt) landed; B(kt+2)+A(kt+1) stay in flight
// Both operands get a full step of latency cover instead of the step tail.
// Bs double-buffered (8->16KB); LDS 32KB total. Traffic identical to R10.
__global__ __launch_bounds__(256, 3)
void ffn1_kernel(const unsigned short* __restrict__ xb,
                 const float* __restrict__ W1,      // [8][768][3072] f32
                 const float* __restrict__ Ws1,     // [768][3072] f32
                 const float* __restrict__ b1, const float* __restrict__ bs1,
                 const int* __restrict__ counts, const int* __restrict__ list,
                 unsigned short* __restrict__ hbuf) {      // [6144][3072]
    __shared__ __align__(16) unsigned short As[2][512 * 8];   // 2 x 8KB
    __shared__ __align__(16) unsigned int Bs32[2][2048];      // 2 x 8KB

    int j = blockIdx.z * 8 + blockIdx.x;    // 0..47
    int y = blockIdx.y;                     // 0..23
    int mt0 = y / 6, ntl = y % 6;           // mt0 0..3, ntl 0..5

    int offv[8];
    { int s = 0;
      #pragma unroll
      for (int e = 0; e < 8; e++) { offv[e] = s; s += counts[e]; } }

    int cnt, hbase, n0, mbase, ntiles;
    const float* Bf;
    const float* bias;
    const int* lst = nullptr;
    if (j < 32) {
        int e = j >> 2, nq = j & 3;
        cnt = counts[e];
        ntiles = (cnt + 127) >> 7;
        mbase = 0;
        hbase = offv[e];
        n0 = nq * 768 + ntl * 128;
        Bf = W1 + (size_t)e * DDIM * HDIM;
        bias = b1 + e * HDIM;
        lst = list + e * TNUM;
    } else {
        int q = j - 32;                     // 0..15
        int ms = q >> 2, nq = q & 3;        // 4 slabs x 4 col-quarters
        mbase = ms * 512;
        ntiles = 4;
        cnt = 1 << 30;
        hbase = 2 * TNUM;
        n0 = nq * 768 + ntl * 128;
        Bf = Ws1;
        bias = bs1;
    }
    if (mt0 >= ntiles) return;

    int tid = threadIdx.x;
    int w = tid >> 6, lane = tid & 63;
    int l15 = lane & 15, quad = lane >> 4;
    int wm = (w & 1) * 64, wn = (w >> 1) * 64;
    int rcA = (w & 1) * 4;
    int rcB = (w >> 1) * 4;
    const int KT = DDIM / 32;   // 24

    int l31 = tid & 31;
    int rp0 = tid >> 5;            // 0..7
    int nlh = l31 >> 2;
    int nll4 = (l31 & 3) * 4;
    int c4 = l31 * 4;

    int ldsoff[2], rowl[2];
    #pragma unroll
    for (int r = 0; r < 2; r++) {
        int rc = r * 4 + w;
        rowl[r] = rc * 16 + l15;
        ldsoff[r] = rc * 512;
    }

    for (int mt = mt0; mt < ntiles; mt += 4) {
        int m0 = mbase + mt * 128;
        const unsigned short* gA[2];
        #pragma unroll
        for (int r = 0; r < 2; r++) {
            int row;
            if (lst) row = lst[min(m0 + rowl[r], cnt - 1)];
            else     row = m0 + rowl[r];
            gA[r] = xb + (size_t)row * DDIM + quad * 8;
        }

        f32x4 zero = {0.f, 0.f, 0.f, 0.f};
        f32x4 acc[4][4];
        #pragma unroll
        for (int i = 0; i < 4; i++)
            #pragma unroll
            for (int jj = 0; jj < 4; jj++) acc[i][jj] = zero;

        float4 Ba[2], Bb[2];
        // prologue: B(0) regs -> pack Bs[0]; then issue [B(1) regs, A(0) cp16]
        #pragma unroll
        for (int p = 0; p < 2; p++) {
            const float* bp = Bf + (size_t)(2 * (p * 8 + rp0)) * HDIM + n0 + c4;
            Ba[p] = *(const float4*)bp;
            Bb[p] = *(const float4*)(bp + HDIM);
        }
        WAITVM(0);
        #pragma unroll
        for (int p = 0; p < 2; p++) {
            int kp = p * 8 + rp0;
            int gb = ((nlh * 64 + (kp >> 2) * 16 + nll4) << 2) + ((kp + nlh) & 3);
            float4 a = Ba[p], b = Bb[p];
            Bs32[0][gb + 0]  = (unsigned int)f2bf(a.x) | ((unsigned int)f2bf(b.x) << 16);
            Bs32[0][gb + 4]  = (unsigned int)f2bf(a.y) | ((unsigned int)f2bf(b.y) << 16);
            Bs32[0][gb + 8]  = (unsigned int)f2bf(a.z) | ((unsigned int)f2bf(b.z) << 16);
            Bs32[0][gb + 12] = (unsigned int)f2bf(a.w) | ((unsigned int)f2bf(b.w) << 16);
        }
        MEMFENCE();
        #pragma unroll
        for (int p = 0; p < 2; p++) {
            const float* bp = Bf + (size_t)(32 + 2 * (p * 8 + rp0)) * HDIM + n0 + c4;
            Ba[p] = *(const float4*)bp;
            Bb[p] = *(const float4*)(bp + HDIM);
        }
        MEMFENCE();   // pin issue order: B(1) loads before A(0) cp16
        #pragma unroll
        for (int r = 0; r < 2; r++) async_cp16(gA[r], &As[0][ldsoff[r]]);

        #pragma unroll 1
        for (int kt = 0; kt < KT; kt++) {
            int cur = kt & 1;
            // phase 1: B(kt+1) regs ready -> pack into Bs[cur^1] (A(kt) may still fly)
            if (kt + 1 < KT) {
                WAITVM(2);
                #pragma unroll
                for (int p = 0; p < 2; p++) {
                    int kp = p * 8 + rp0;
                    int gb = ((nlh * 64 + (kp >> 2) * 16 + nll4) << 2) + ((kp + nlh) & 3);
                    float4 a = Ba[p], b = Bb[p];
                    Bs32[cur ^ 1][gb + 0]  = (unsigned int)f2bf(a.x) | ((unsigned int)f2bf(b.x) << 16);
                    Bs32[cur ^ 1][gb + 4]  = (unsigned int)f2bf(a.y) | ((unsigned int)f2bf(b.y) << 16);
                    Bs32[cur ^ 1][gb + 8]  = (unsigned int)f2bf(a.z) | ((unsigned int)f2bf(b.z) << 16);
                    Bs32[cur ^ 1][gb + 12] = (unsigned int)f2bf(a.w) | ((unsigned int)f2bf(b.w) << 16);
                }
            }
            // phase 2: issue next loads — B(kt+2) first, then A(kt+1) (vmcnt order)
            if (kt + 2 < KT) {
                int ko = (kt + 2) * 32;
                #pragma unroll
                for (int p = 0; p < 2; p++) {
                    const float* bp = Bf + (size_t)(ko + 2 * (p * 8 + rp0)) * HDIM + n0 + c4;
                    Ba[p] = *(const float4*)bp;
                    Bb[p] = *(const float4*)(bp + HDIM);
                }
                MEMFENCE();
            }
            if (kt + 1 < KT) {
                int ka = (kt + 1) * 32;
                #pragma unroll
                for (int r = 0; r < 2; r++)
                    async_cp16(gA[r] + ka, &As[cur ^ 1][ldsoff[r]]);
            }
            // phase 3: drain A(kt) only; younger loads stay in flight across barrier
            if (kt + 2 < KT)      { WAITVM(6); }
            else if (kt + 1 < KT) { WAITVM(2); }
            else                  { WAITVM(0); }
            WAITLGKM();
            __builtin_amdgcn_s_barrier();
            MEMFENCE();
            // phase 4: MFMA on As[cur], Bs[cur]
            bf16x8 af[4], bv[4];
            #pragma unroll
            for (int i = 0; i < 4; i++)
                af[i] = *(const bf16x8*)&As[cur][((rcA + i) * 64 + quad * 16 + l15) * 8];
            #pragma unroll
            for (int jj = 0; jj < 4; jj++) {
                uint4 Wv = *(const uint4*)&Bs32[cur][((rcB + jj) * 64 + quad * 16 + l15) << 2];
                unsigned int s0 = Wv.x, s1 = Wv.y, s2 = Wv.z, s3 = Wv.w;
                unsigned int t0, t1, t2, t3;
                if (jj == 0)      { t0 = s0; t1 = s1; t2 = s2; t3 = s3; }
                else if (jj == 1) { t0 = s1; t1 = s2; t2 = s3; t3 = s0; }
                else if (jj == 2) { t0 = s2; t1 = s3; t2 = s0; t3 = s1; }
                else              { t0 = s3; t1 = s0; t2 = s1; t3 = s2; }
                uint4 L; L.x = t0; L.y = t1; L.z = t2; L.w = t3;
                __builtin_memcpy(&bv[jj], &L, 16);
            }
            #pragma unroll
            for (int i = 0; i < 4; i++)
                #pragma unroll
                for (int jj = 0; jj < 4; jj++)
                    acc[i][jj] = __builtin_amdgcn_mfma_f32_16x16x32_bf16(af[i], bv[jj], acc[i][jj], 0, 0, 0);
            MEMFENCE();
            __builtin_amdgcn_s_barrier();
            MEMFENCE();
        }

        #pragma unroll
        for (int i = 0; i < 4; i++) {
            int rbase = m0 + wm + i * 16 + quad * 4;
            #pragma unroll
            for (int jj = 0; jj < 4; jj++) {
                int gc = n0 + wn + jj * 16 + l15;
                float bvl = bias[gc];
                #pragma unroll
                for (int r = 0; r < 4; r++) {
                    int gr = rbase + r;
                    if (gr < cnt) {
                        float v = acc[i][jj][r] + bvl;
                        v = v > 0.f ? v : 0.01f * v;
                        hbuf[(size_t)(hbase + gr) * HDIM + gc] = f2bf(v);
                    }
                }
            }
        }
    }
}

// ---------------- GEMM layer 2 (R7-exact): BM=128, BN=128, BK=32 ----------------
__global__ __launch_bounds__(256, 4)
void ffn2_kernel(const unsigned short* __restrict__ hbuf,
                 const unsigned short* __restrict__ W2t,   // [8][768][3072]
                 const unsigned short* __restrict__ Ws2t,  // [768][3072]
                 const int* __restrict__ counts,
                 float* __restrict__ ybuf) {               // [2][6144][768]
    __shared__ __align__(16) unsigned short As[2][512 * 8];   // 2 x 8KB
    __shared__ __align__(16) unsigned short Bs[2][512 * 8];   // 2 x 8KB (32KB total)

    int j = blockIdx.z * 8 + blockIdx.x;    // 0..23
    int y = blockIdx.y;                     // 0..23
    int mt0 = y / 6, ntl = y % 6;           // mt0 0..3, ntl 0..5
    int n0 = ntl * 128;

    int offv[8];
    { int s = 0;
      #pragma unroll
      for (int e = 0; e < 8; e++) { offv[e] = s; s += counts[e]; } }

    int cnt, hbase, mbase, kh, ntiles;
    const unsigned short* Bmat;
    if (j < 16) {
        int e = j >> 1; kh = j & 1;
        cnt = counts[e];
        ntiles = (cnt + 127) >> 7;
        mbase = 0;
        hbase = offv[e];
        Bmat = W2t + (size_t)e * DDIM * HDIM;
    } else {
        int q = j - 16;
        int ms = q >> 1; kh = q & 1;
        mbase = ms * 512;
        ntiles = 4;
        cnt = 1 << 30;
        hbase = 2 * TNUM;
        Bmat = Ws2t;
    }
    if (mt0 >= ntiles) return;
    int kbase = kh * (HDIM / 2);

    int tid = threadIdx.x;
    int w = tid >> 6, lane = tid & 63;
    int l15 = lane & 15, quad = lane >> 4;
    int wm = (w & 1) * 64, wn = (w >> 1) * 64;
    int rcA = (w & 1) * 4;
    int rcB = (w >> 1) * 4;
    const int KT = (HDIM / 2) / 32;   // 48

    const unsigned short* gB[2];
    int ldsoff[2], rowl[2];
    #pragma unroll
    for (int r = 0; r < 2; r++) {
        int rc = r * 4 + w;
        rowl[r] = rc * 16 + l15;
        ldsoff[r] = rc * 512;
        gB[r] = Bmat + (size_t)(n0 + rowl[r]) * HDIM + kbase + quad * 8;
    }
    float* yb = ybuf + (size_t)kh * 6144 * DDIM;

    for (int mt = mt0; mt < ntiles; mt += 4) {
        int m0 = mbase + mt * 128;
        const unsigned short* gA[2];
        #pragma unroll
        for (int r = 0; r < 2; r++) {
            int row = (j < 16) ? min(m0 + rowl[r], cnt - 1) : (m0 + rowl[r]);
            gA[r] = hbuf + (size_t)(hbase + row) * HDIM + kbase + quad * 8;
        }

        f32x4 zero = {0.f, 0.f, 0.f, 0.f};
        f32x4 acc[4][4];
        #pragma unroll
        for (int i = 0; i < 4; i++)
            #pragma unroll
            for (int jj = 0; jj < 4; jj++) acc[i][jj] = zero;

        // prologue: tiles 0 and 1
        #pragma unroll
        for (int t = 0; t < 2; t++)
            #pragma unroll
            for (int r = 0; r < 2; r++) {
                async_cp16(gA[r] + t * 32, &As[t][ldsoff[r]]);
                async_cp16(gB[r] + t * 32, &Bs[t][ldsoff[r]]);
            }

        #pragma unroll 1
        for (int kt = 0; kt < KT; kt++) {
            if (kt == KT - 1) { WAITVM(0); } else { WAITVM(4); }   // oldest tile arrived
            __builtin_amdgcn_s_barrier();
            MEMFENCE();
            int cur = kt & 1;
            bf16x8 af[4], bv[4];
            #pragma unroll
            for (int i = 0; i < 4; i++)
                af[i] = *(const bf16x8*)&As[cur][((rcA + i) * 64 + quad * 16 + l15) * 8];
            #pragma unroll
            for (int jj = 0; jj < 4; jj++)
                bv[jj] = *(const bf16x8*)&Bs[cur][((rcB + jj) * 64 + quad * 16 + l15) * 8];
            #pragma unroll
            for (int i = 0; i < 4; i++)
                #pragma unroll
                for (int jj = 0; jj < 4; jj++)
                    acc[i][jj] = __builtin_amdgcn_mfma_f32_16x16x32_bf16(af[i], bv[jj], acc[i][jj], 0, 0, 0);
            MEMFENCE();
            __builtin_amdgcn_s_barrier();      // all waves done reading buf[cur]
            MEMFENCE();
            if (kt + 2 < KT) {
                int ko = (kt + 2) * 32;
                #pragma unroll
                for (int r = 0; r < 2; r++) {
                    async_cp16(gA[r] + ko, &As[cur][ldsoff[r]]);
                    async_cp16(gB[r] + ko, &Bs[cur][ldsoff[r]]);
                }
            }
        }

        #pragma unroll
        for (int i = 0; i < 4; i++) {
            int rbase = m0 + wm + i * 16 + quad * 4;
            #pragma unroll
            for (int r = 0; r < 4; r++) {
                int gr = rbase + r;
                if (gr >= cnt) continue;
                float* orow = yb + (size_t)(hbase + gr) * DDIM + n0 + wn;
                #pragma unroll
                for (int jj = 0; jj < 4; jj++)
                    orow[jj * 16 + l15] = acc[i][jj][r];
            }
        }
    }
}

// ---------------- final mix ----------------
__global__ void mix_kernel(const float* __restrict__ ybuf, const int* __restrict__ inv,
                           const float* __restrict__ tokp, const int* __restrict__ counts,
                           const float* __restrict__ b2, const float* __restrict__ bs2,
                           const float* __restrict__ alpha, const float* __restrict__ beta,
                           float* __restrict__ out) {
    int t = blockIdx.x;
    int c = threadIdx.x * 4;
    int offv[8];
    { int s = 0;
      #pragma unroll
      for (int e = 0; e < 8; e++) { offv[e] = s; s += counts[e]; } }
    float a = alpha[0], bsc = beta[0];
    float m = fmaxf(a, bsc);
    float ea = expf(a - m), eb = expf(bsc - m);
    float is = 1.f / (ea + eb);
    float ws = ea * is, wmx = eb * is;

    int i0 = inv[t * 2 + 0], i1 = inv[t * 2 + 1];
    int e0 = i0 >> 16, sl0 = i0 & 0xFFFF;
    int e1 = i1 >> 16, sl1 = i1 & 0xFFFF;
    float p0 = tokp[t * 2 + 0], p1 = tokp[t * 2 + 1];
    size_t rA = (size_t)(offv[e0] + sl0) * DDIM + c;
    size_t rB = (size_t)(offv[e1] + sl1) * DDIM + c;
    size_t rS = (size_t)(2 * TNUM + t) * DDIM + c;
    const float* y0 = ybuf;
    const float* y1 = ybuf + (size_t)6144 * DDIM;
    float4 vA0 = *(const float4*)(y0 + rA);
    float4 vA1 = *(const float4*)(y1 + rA);
    float4 vB0 = *(const float4*)(y0 + rB);
    float4 vB1 = *(const float4*)(y1 + rB);
    float4 vS0 = *(const float4*)(y0 + rS);
    float4 vS1 = *(const float4*)(y1 + rS);
    float4 bA = *(const float4*)(b2 + e0 * DDIM + c);
    float4 bB = *(const float4*)(b2 + e1 * DDIM + c);
    float4 bS = *(const float4*)(bs2 + c);
    float4 o;
    o.x = ws * (vS0.x + vS1.x + bS.x) + wmx * (p0 * (vA0.x + vA1.x + bA.x) + p1 * (vB0.x + vB1.x + bB.x));
    o.y = ws * (vS0.y + vS1.y + bS.y) + wmx * (p0 * (vA0.y + vA1.y + bA.y) + p1 * (vB0.y + vB1.y + bB.y));
    o.z = ws * (vS0.z + vS1.z + bS.z) + wmx * (p0 * (vA0.z + vA1.z + bA.z) + p1 * (vB0.z + vB1.z + bB.z));
    o.w = ws * (vS0.w + vS1.w + bS.w) + wmx * (p0 * (vA0.w + vA1.w + bA.w) + p1 * (vB0.w + vB1.w + bB.w));
    *(float4*)(out + (size_t)t * DDIM + c) = o;
}

extern "C" void kernel_launch(void* const* d_in, const int* in_sizes, int n_in,
                              void* d_out, int out_size, void* d_ws, size_t ws_size,
                              hipStream_t stream) {
    const float* x     = (const float*)d_in[0];
    const float* noise = (const float*)d_in[1];
    const float* Wr    = (const float*)d_in[2];
    const float* br    = (const float*)d_in[3];
    const float* W1    = (const float*)d_in[4];
    const float* b1    = (const float*)d_in[5];
    const float* W2    = (const float*)d_in[6];
    const float* b2    = (const float*)d_in[7];
    const float* Ws1   = (const float*)d_in[8];
    const float* bs1   = (const float*)d_in[9];
    const float* Ws2   = (const float*)d_in[10];
    const float* bs2   = (const float*)d_in[11];
    const float* alpha = (const float*)d_in[12];
    const float* beta  = (const float*)d_in[13];

    char* ws = (char*)d_ws;
    size_t off = 0;
    auto alloc = [&](size_t bytes) -> char* {
        char* p = ws + off;
        off = (off + bytes + 255) & ~(size_t)255;
        return p;
    };
    int*   counts = (int*)  alloc(ENUM * 4);
    int*   list   = (int*)  alloc((size_t)ENUM * TNUM * 4);
    int*   inv    = (int*)  alloc((size_t)TNUM * 2 * 4);
    float* tokp   = (float*)alloc((size_t)TNUM * 2 * 4);
    unsigned short* xb   = (unsigned short*)alloc((size_t)TNUM * DDIM * 2);
    float* ybuf          = (float*)alloc((size_t)2 * 6144 * DDIM * 4);              // 37.75 MB
    unsigned short* W2t  = (unsigned short*)alloc((size_t)ENUM * DDIM * HDIM * 2);  // 36 MB
    unsigned short* Ws2t = (unsigned short*)alloc((size_t)DDIM * HDIM * 2);         // 4.5 MB
    unsigned short* hbuf = (unsigned short*)alloc((size_t)(3 * TNUM) * HDIM * 2);   // 37.75 MB
    if (off > ws_size) {
        fprintf(stderr, "kernel_launch: workspace too small (need %zu, have %zu)\n", off, ws_size);
        return;
    }

    hipMemsetAsync(counts, 0, ENUM * 4, stream);

    // k1: transw(W2,Ws2) + cast + router (1296 + 768 + 512 blocks)
    pre_kernel<<<dim3(2576), dim3(256), 0, stream>>>(x, noise, Wr, br, W2, Ws2,
                                                     W2t, Ws2t, xb, counts, list, inv, tokp);
    // k2: ffn1 fused-transpose split-wait, 48 balanced jobs (z=6), 32KB LDS
    ffn1_kernel<<<dim3(8, 24, 6), dim3(256), 0, stream>>>(xb, W1, Ws1, b1, bs1, counts, list, hbuf);
    // k3: ffn2 BM=128 (R7-exact), 24 jobs, 32KB LDS, 576 blocks
    ffn2_kernel<<<dim3(8, 24, 3), dim3(256), 0, stream>>>(hbuf, W2t, Ws2t, counts, ybuf);
    // k4: mix
    mix_kernel<<<dim3(TNUM), dim3(192), 0, stream>>>(ybuf, inv, tokp, counts, b2, bs2,
                                                     alpha, beta, (float*)d_out);
}